// Round 8
// baseline (632.659 us; speedup 1.0000x reference)
//
#include <hip/hip_runtime.h>

#define HDIM 128
#define GCOUNT 64

// ---- bf16 helpers (manual, RNE) ----
__device__ __forceinline__ float bfl(unsigned u) { return __uint_as_float(u << 16); }
__device__ __forceinline__ float bfh(unsigned u) { return __uint_as_float(u & 0xffff0000u); }
__device__ __forceinline__ unsigned short f2bf(float f) {
  unsigned u = __float_as_uint(f);
  unsigned r = (u + 0x7fffu + ((u >> 16) & 1u)) >> 16;
  return (unsigned short)r;
}
__device__ __forceinline__ unsigned pk2(float a, float b) {
  return (unsigned)f2bf(a) | ((unsigned)f2bf(b) << 16);
}

typedef __attribute__((ext_vector_type(8))) short short8;
typedef __attribute__((ext_vector_type(4))) float f32x4;

// ------- setup: zero cnt + pooled + gcnt, transpose 3 weights to bf16 hi/lo -------

__global__ void setup_kernel(const float* __restrict__ W0, const float* __restrict__ W1,
                             const float* __restrict__ W2,
                             unsigned short* __restrict__ h0, unsigned short* __restrict__ l0,
                             unsigned short* __restrict__ h1, unsigned short* __restrict__ l1,
                             unsigned short* __restrict__ h2, unsigned short* __restrict__ l2,
                             int* __restrict__ cnt, int n,
                             float* __restrict__ pooled, float* __restrict__ gcnt, int nb) {
  int b = blockIdx.x, t = threadIdx.x;
  if (b < 192) {
    int w = b >> 6;
    int idx = (b & 63) * 256 + t;
    const float* W = (w == 0) ? W0 : (w == 1) ? W1 : W2;
    unsigned short* hi = (w == 0) ? h0 : (w == 1) ? h1 : h2;
    unsigned short* lo = (w == 0) ? l0 : (w == 1) ? l1 : l2;
    int k = idx >> 7, nn = idx & 127;
    float wv = W[idx];
    unsigned short h = f2bf(wv);
    float hf = __uint_as_float((unsigned)h << 16);
    unsigned short l = f2bf(wv - hf);
    hi[nn * 128 + k] = h;
    lo[nn * 128 + k] = l;
  } else if (b < 192 + nb) {
    int i = (b - 192) * 256 + t;
    if (i < n) cnt[i] = 0;
  } else {
    int i = (b - 192 - nb) * 256 + t;
    if (i < GCOUNT * HDIM) pooled[i] = 0.f;
    else if (i - GCOUNT * HDIM < GCOUNT) gcnt[i - GCOUNT * HDIM] = 0.f;
  }
}

// ------- degree histogram: atomic return value = stable rank (4/thread, 2x blocks) -------

__global__ void hist_kernel(const int* __restrict__ dst, int* __restrict__ cnt,
                            int* __restrict__ rank, int E) {
  int i0 = blockIdx.x * 1024 + threadIdx.x;
  #pragma unroll
  for (int j = 0; j < 4; j++) {
    int e = i0 + j * 256;
    if (e < E) rank[e] = atomicAdd(&cnt[dst[e]], 1);
  }
}

// ------- scan1: per-block exclusive scan of cnt + dinv -------

__global__ void scan1(const int* __restrict__ cnt, int* __restrict__ row_ptr,
                      int* __restrict__ bsum, float* __restrict__ dinv, int n) {
  __shared__ int sh[256];
  int t = threadIdx.x;
  int i = blockIdx.x * 256 + t;
  int v = (i < n) ? cnt[i] : 0;
  if (i < n) dinv[i] = rsqrtf((float)v + 1.0f);
  sh[t] = v;
  __syncthreads();
  for (int off = 1; off < 256; off <<= 1) {
    int u = (t >= off) ? sh[t - off] : 0;
    __syncthreads();
    sh[t] += u;
    __syncthreads();
  }
  if (i < n) row_ptr[i] = sh[t] - v;
  if (t == 255) bsum[blockIdx.x] = sh[255];
}

// ------- scan23: each block redundantly scans bsum, applies offset -------

__global__ void scan23(int* __restrict__ rowp, const int* __restrict__ bsum,
                       int nb, int n, int E) {
  __shared__ int sh[512];
  int t = threadIdx.x;
  sh[t] = (t < nb) ? bsum[t] : 0;
  __syncthreads();
  for (int off = 1; off < 512; off <<= 1) {
    int u = (t >= off) ? sh[t - off] : 0;
    __syncthreads();
    sh[t] += u;
    __syncthreads();
  }
  #pragma unroll
  for (int k = 0; k < 2; k++) {
    int i = blockIdx.x * 1024 + k * 512 + t;
    if (i < n) {
      int j = i >> 8;
      int add = j ? sh[j - 1] : 0;
      rowp[i] += add;
    }
  }
  if (blockIdx.x == 0 && t == 0) rowp[n] = E;
}

// ------- fill (atomic-free scatter) + prescale, one dispatch -------

__global__ void fill_prescale(const int* __restrict__ src, const int* __restrict__ dst,
                              const int* __restrict__ rank, const int* __restrict__ rowp,
                              int* __restrict__ col, int E,
                              const float* __restrict__ x, const float* __restrict__ dinv,
                              unsigned short* __restrict__ S, int n4, int fb) {
  int b = blockIdx.x, t = threadIdx.x;
  if (b < fb) {
    int i0 = b * 2048 + t;
    #pragma unroll
    for (int j = 0; j < 8; j++) {
      int e = i0 + j * 256;
      if (e < E) col[rowp[dst[e]] + rank[e]] = src[e];
    }
  } else {
    int i = (b - fb) * 256 + t;
    if (i < n4) {
      float4 v = ((const float4*)x)[i];
      float d = dinv[i >> 5];
      ushort4 o;
      o.x = f2bf(v.x * d); o.y = f2bf(v.y * d); o.z = f2bf(v.z * d); o.w = f2bf(v.w * d);
      ((ushort4*)S)[i] = o;
    }
  }
}

// ------- aggregation: ONE ROW PER WAVE (zero intra-wave divergence) -------
// Lane owns cols 2*lane, 2*lane+1 (one dword). col[e] is wave-uniform -> scalar load.
// 8-deep main unroll, 4-deep remainder to keep gathers in flight.

__global__ void agg_bf16(const unsigned* __restrict__ S, const float* __restrict__ dinv,
                         const int* __restrict__ rowp, const int* __restrict__ col,
                         unsigned* __restrict__ OUT, int n) {
  int w = (blockIdx.x * blockDim.x + threadIdx.x) >> 6;
  int lane = threadIdx.x & 63;
  if (w >= n) return;
  size_t base = (size_t)w * 64 + lane;
  unsigned u = S[base];
  float a0 = bfl(u), a1 = bfh(u);
  int e0 = rowp[w], e1 = rowp[w + 1];
  int e = e0;
  for (; e + 7 < e1; e += 8) {
    int s0 = col[e],     s1 = col[e + 1], s2 = col[e + 2], s3 = col[e + 3];
    int s4 = col[e + 4], s5 = col[e + 5], s6 = col[e + 6], s7 = col[e + 7];
    unsigned v0 = S[(size_t)s0 * 64 + lane];
    unsigned v1 = S[(size_t)s1 * 64 + lane];
    unsigned v2 = S[(size_t)s2 * 64 + lane];
    unsigned v3 = S[(size_t)s3 * 64 + lane];
    unsigned v4 = S[(size_t)s4 * 64 + lane];
    unsigned v5 = S[(size_t)s5 * 64 + lane];
    unsigned v6 = S[(size_t)s6 * 64 + lane];
    unsigned v7 = S[(size_t)s7 * 64 + lane];
    a0 += bfl(v0); a1 += bfh(v0);
    a0 += bfl(v1); a1 += bfh(v1);
    a0 += bfl(v2); a1 += bfh(v2);
    a0 += bfl(v3); a1 += bfh(v3);
    a0 += bfl(v4); a1 += bfh(v4);
    a0 += bfl(v5); a1 += bfh(v5);
    a0 += bfl(v6); a1 += bfh(v6);
    a0 += bfl(v7); a1 += bfh(v7);
  }
  for (; e + 3 < e1; e += 4) {
    int s0 = col[e], s1 = col[e + 1], s2 = col[e + 2], s3 = col[e + 3];
    unsigned v0 = S[(size_t)s0 * 64 + lane];
    unsigned v1 = S[(size_t)s1 * 64 + lane];
    unsigned v2 = S[(size_t)s2 * 64 + lane];
    unsigned v3 = S[(size_t)s3 * 64 + lane];
    a0 += bfl(v0); a1 += bfh(v0);
    a0 += bfl(v1); a1 += bfh(v1);
    a0 += bfl(v2); a1 += bfh(v2);
    a0 += bfl(v3); a1 += bfh(v3);
  }
  for (; e < e1; e++) {
    unsigned v = S[(size_t)col[e] * 64 + lane];
    a0 += bfl(v); a1 += bfh(v);
  }
  float d = dinv[w];
  OUT[base] = pk2(a0 * d, a1 * d);
}

// ------- MFMA GEMM: Y = relu(A @ W + b) [* dinv], A bf16 [n,128] -------

__global__ __launch_bounds__(256) void gemm_mfma(
    const uint4* __restrict__ A, const uint4* __restrict__ WThi, const uint4* __restrict__ WTlo,
    const float* __restrict__ bias, const float* __restrict__ dinv, int do_scale,
    unsigned short* __restrict__ Y, int n) {
  int t = threadIdx.x;
  int lane = t & 63, wv = t >> 6;
  int m = lane & 15, quad = lane >> 4;
  int row0 = blockIdx.x * 64 + wv * 16;
  int arow = row0 + m;
  f32x4 acc[8];
  #pragma unroll
  for (int i = 0; i < 8; i++) acc[i] = (f32x4){0.f, 0.f, 0.f, 0.f};
  #pragma unroll
  for (int kb = 0; kb < 4; kb++) {
    uint4 av = (arow < n) ? A[(size_t)arow * 16 + kb * 4 + quad] : make_uint4(0, 0, 0, 0);
    short8 af = __builtin_bit_cast(short8, av);
    #pragma unroll
    for (int nt = 0; nt < 8; nt++) {
      int colr = nt * 16 + m;
      uint4 bh = WThi[(size_t)colr * 16 + kb * 4 + quad];
      uint4 bl = WTlo[(size_t)colr * 16 + kb * 4 + quad];
      acc[nt] = __builtin_amdgcn_mfma_f32_16x16x32_bf16(af, __builtin_bit_cast(short8, bh), acc[nt], 0, 0, 0);
      acc[nt] = __builtin_amdgcn_mfma_f32_16x16x32_bf16(af, __builtin_bit_cast(short8, bl), acc[nt], 0, 0, 0);
    }
  }
  #pragma unroll
  for (int r = 0; r < 4; r++) {
    int grow = row0 + quad * 4 + r;
    if (grow < n) {
      float sc = do_scale ? dinv[grow] : 1.0f;
      #pragma unroll
      for (int nt = 0; nt < 8; nt++) {
        int colr = nt * 16 + m;
        float v = fmaxf(acc[nt][r] + bias[colr], 0.f) * sc;
        Y[(size_t)grow * 128 + colr] = f2bf(v);
      }
    }
  }
}

// ------- mean pool (batch sorted, bf16 input; parallel) -------

__global__ void pool_kernel(const unsigned short* __restrict__ X, const int* __restrict__ batch,
                            float* __restrict__ pooled, float* __restrict__ gcnt, int n) {
  int t = threadIdx.x;             // 128 threads = columns
  int r0 = blockIdx.x * 64;
  if (r0 >= n) return;
  int r1 = min(r0 + 64, n);
  int g = batch[r0];
  float acc = 0.f, cl = 0.f;
  for (int r = r0; r < r1; r++) {
    int gr = batch[r];
    if (gr != g) {
      atomicAdd(&pooled[g * HDIM + t], acc);
      if (t == 0) atomicAdd(&gcnt[g], cl);
      acc = 0.f; cl = 0.f; g = gr;
    }
    acc += __uint_as_float((unsigned)X[(size_t)r * HDIM + t] << 16);
    cl += 1.f;
  }
  atomicAdd(&pooled[g * HDIM + t], acc);
  if (t == 0) atomicAdd(&gcnt[g], cl);
}

// ------- classifier head -------

__global__ void cls_kernel(const float* __restrict__ pooled, const float* __restrict__ gcnt,
                           const float* __restrict__ Wc1, const float* __restrict__ bc1,
                           const float* __restrict__ Wc2, const float* __restrict__ bc2,
                           float* __restrict__ out) {
  __shared__ float p[HDIM];
  __shared__ float r0s[HDIM], r1s[HDIM];
  int g = blockIdx.x, t = threadIdx.x;
  float c = fmaxf(gcnt[g], 1.0f);
  p[t] = pooled[g * HDIM + t] / c;
  __syncthreads();
  float acc = bc1[t];
  for (int k = 0; k < HDIM; k++) {
    acc += p[k] * (Wc1[k * HDIM + t] + Wc1[(HDIM + k) * HDIM + t]);
  }
  float h = fmaxf(acc, 0.f);
  r0s[t] = h * Wc2[t * 2 + 0];
  r1s[t] = h * Wc2[t * 2 + 1];
  __syncthreads();
  for (int s2 = 64; s2 > 0; s2 >>= 1) {
    if (t < s2) { r0s[t] += r0s[t + s2]; r1s[t] += r1s[t + s2]; }
    __syncthreads();
  }
  if (t == 0) {
    out[g * 2 + 0] = r0s[0] + bc2[0];
    out[g * 2 + 1] = r1s[0] + bc2[1];
  }
}

// ------- launch -------

extern "C" void kernel_launch(void* const* d_in, const int* in_sizes, int n_in,
                              void* d_out, int out_size, void* d_ws, size_t ws_size,
                              hipStream_t stream) {
  const float* x   = (const float*)d_in[0];
  const int*   ei  = (const int*)d_in[1];
  const int*   bat = (const int*)d_in[2];
  const float* W0  = (const float*)d_in[3];
  const float* b0  = (const float*)d_in[4];
  const float* W1  = (const float*)d_in[5];
  const float* b1  = (const float*)d_in[6];
  const float* W2  = (const float*)d_in[7];
  const float* b2  = (const float*)d_in[8];
  const float* Wc1 = (const float*)d_in[9];
  const float* bc1 = (const float*)d_in[10];
  const float* Wc2 = (const float*)d_in[11];
  const float* bc2 = (const float*)d_in[12];
  float* out = (float*)d_out;

  int N = in_sizes[0] / HDIM;
  int E = in_sizes[1] / 2;
  const int* src = ei;
  const int* dst = ei + E;

  char* ws = (char*)d_ws;
  size_t off = 0;
  auto alloc = [&](size_t bytes) -> void* {
    void* p = (void*)(ws + off);
    off += (bytes + 511) & ~(size_t)511;
    return p;
  };
  unsigned short* buf0 = (unsigned short*)alloc((size_t)N * HDIM * 2);  // state
  unsigned short* buf1 = (unsigned short*)alloc((size_t)N * HDIM * 2);  // agg out
  float* dinv = (float*)alloc((size_t)N * 4);
  int*   cnt  = (int*)alloc((size_t)N * 4);
  int*   rowp = (int*)alloc((size_t)(N + 1) * 4);
  int*   col  = (int*)alloc((size_t)E * 4);
  int*   rank = (int*)alloc((size_t)E * 4);
  float* pooled = (float*)alloc((size_t)GCOUNT * HDIM * 4);
  float* gcnt   = (float*)alloc((size_t)GCOUNT * 4);
  unsigned short* wt_hi[3], *wt_lo[3];
  for (int i = 0; i < 3; i++) {
    wt_hi[i] = (unsigned short*)alloc(HDIM * HDIM * 2);
    wt_lo[i] = (unsigned short*)alloc(HDIM * HDIM * 2);
  }
  int nb = (N + 255) / 256;
  int* bsum = (int*)alloc((size_t)nb * 4);

  // 1. setup: zero cnt/pooled/gcnt + weight transposes
  int pz = (GCOUNT * HDIM + GCOUNT + 255) / 256;
  setup_kernel<<<192 + nb + pz, 256, 0, stream>>>(W0, W1, W2, wt_hi[0], wt_lo[0],
      wt_hi[1], wt_lo[1], wt_hi[2], wt_lo[2], cnt, N, pooled, gcnt, nb);

  // 2. histogram (+rank), 4 edges/thread
  int eb4 = (E + 1023) / 1024;
  hist_kernel<<<eb4, 256, 0, stream>>>(dst, cnt, rank, E);

  // 3-4. scans (+dinv)
  scan1<<<nb, 256, 0, stream>>>(cnt, rowp, bsum, dinv, N);
  scan23<<<(N + 1023) / 1024, 512, 0, stream>>>(rowp, bsum, nb, N, E);

  // 5. fill CSR + prescale state
  int eb8 = (E + 2047) / 2048;
  int n4 = N * 32;
  int pb = (n4 + 255) / 256;
  fill_prescale<<<eb8 + pb, 256, 0, stream>>>(src, dst, rank, rowp, col, E,
      x, dinv, buf0, n4, eb8);

  // 6-11. agg (1 row/wave) + MFMA gemm, ping-pong
  int aggBlocks = (N + 3) / 4;
  int gemmBlocks = (N + 63) / 64;

  agg_bf16<<<aggBlocks, 256, 0, stream>>>((const unsigned*)buf0, dinv, rowp, col, (unsigned*)buf1, N);
  gemm_mfma<<<gemmBlocks, 256, 0, stream>>>((const uint4*)buf1, (const uint4*)wt_hi[0],
      (const uint4*)wt_lo[0], b0, dinv, 1, buf0, N);

  agg_bf16<<<aggBlocks, 256, 0, stream>>>((const unsigned*)buf0, dinv, rowp, col, (unsigned*)buf1, N);
  gemm_mfma<<<gemmBlocks, 256, 0, stream>>>((const uint4*)buf1, (const uint4*)wt_hi[1],
      (const uint4*)wt_lo[1], b1, dinv, 1, buf0, N);

  agg_bf16<<<aggBlocks, 256, 0, stream>>>((const unsigned*)buf0, dinv, rowp, col, (unsigned*)buf1, N);
  gemm_mfma<<<gemmBlocks, 256, 0, stream>>>((const uint4*)buf1, (const uint4*)wt_hi[2],
      (const uint4*)wt_lo[2], b2, dinv, 0, buf0, N);

  // 12-13. parallel pool + classifier
  pool_kernel<<<(N + 63) / 64, 128, 0, stream>>>(buf0, bat, pooled, gcnt, N);
  cls_kernel<<<GCOUNT, HDIM, 0, stream>>>(pooled, gcnt, Wc1, bc1, Wc2, bc2, out);
}

// Round 9
// 546.172 us; speedup vs baseline: 1.1584x; 1.1584x over previous
//
#include <hip/hip_runtime.h>

#define HDIM 128
#define GCOUNT 64

// ---- bf16 helpers (manual, RNE) ----
__device__ __forceinline__ float bfl(unsigned u) { return __uint_as_float(u << 16); }
__device__ __forceinline__ float bfh(unsigned u) { return __uint_as_float(u & 0xffff0000u); }
__device__ __forceinline__ unsigned short f2bf(float f) {
  unsigned u = __float_as_uint(f);
  unsigned r = (u + 0x7fffu + ((u >> 16) & 1u)) >> 16;
  return (unsigned short)r;
}
__device__ __forceinline__ unsigned pk2(float a, float b) {
  return (unsigned)f2bf(a) | ((unsigned)f2bf(b) << 16);
}

typedef __attribute__((ext_vector_type(8))) short short8;
typedef __attribute__((ext_vector_type(4))) float f32x4;

// int8 quant helpers
__device__ __forceinline__ unsigned qb(float v, float rinv) {
  int q = (int)rintf(v * rinv);
  return (unsigned)(q & 0xff);
}

// ------- setup: zero cnt + pooled + gcnt, transpose 3 weights to bf16 hi/lo -------

__global__ void setup_kernel(const float* __restrict__ W0, const float* __restrict__ W1,
                             const float* __restrict__ W2,
                             unsigned short* __restrict__ h0, unsigned short* __restrict__ l0,
                             unsigned short* __restrict__ h1, unsigned short* __restrict__ l1,
                             unsigned short* __restrict__ h2, unsigned short* __restrict__ l2,
                             int* __restrict__ cnt, int n,
                             float* __restrict__ pooled, float* __restrict__ gcnt, int nb) {
  int b = blockIdx.x, t = threadIdx.x;
  if (b < 192) {
    int w = b >> 6;
    int idx = (b & 63) * 256 + t;
    const float* W = (w == 0) ? W0 : (w == 1) ? W1 : W2;
    unsigned short* hi = (w == 0) ? h0 : (w == 1) ? h1 : h2;
    unsigned short* lo = (w == 0) ? l0 : (w == 1) ? l1 : l2;
    int k = idx >> 7, nn = idx & 127;
    float wv = W[idx];
    unsigned short h = f2bf(wv);
    float hf = __uint_as_float((unsigned)h << 16);
    unsigned short l = f2bf(wv - hf);
    hi[nn * 128 + k] = h;
    lo[nn * 128 + k] = l;
  } else if (b < 192 + nb) {
    int i = (b - 192) * 256 + t;
    if (i < n) cnt[i] = 0;
  } else {
    int i = (b - 192 - nb) * 256 + t;
    if (i < GCOUNT * HDIM) pooled[i] = 0.f;
    else if (i - GCOUNT * HDIM < GCOUNT) gcnt[i - GCOUNT * HDIM] = 0.f;
  }
}

// ------- degree histogram: atomic return value = stable rank -------

__global__ void hist_kernel(const int* __restrict__ dst, int* __restrict__ cnt,
                            int* __restrict__ rank, int E) {
  int i0 = blockIdx.x * 1024 + threadIdx.x;
  #pragma unroll
  for (int j = 0; j < 4; j++) {
    int e = i0 + j * 256;
    if (e < E) rank[e] = atomicAdd(&cnt[dst[e]], 1);
  }
}

// ------- scan1 -------

__global__ void scan1(const int* __restrict__ cnt, int* __restrict__ row_ptr,
                      int* __restrict__ bsum, float* __restrict__ dinv, int n) {
  __shared__ int sh[256];
  int t = threadIdx.x;
  int i = blockIdx.x * 256 + t;
  int v = (i < n) ? cnt[i] : 0;
  if (i < n) dinv[i] = rsqrtf((float)v + 1.0f);
  sh[t] = v;
  __syncthreads();
  for (int off = 1; off < 256; off <<= 1) {
    int u = (t >= off) ? sh[t - off] : 0;
    __syncthreads();
    sh[t] += u;
    __syncthreads();
  }
  if (i < n) row_ptr[i] = sh[t] - v;
  if (t == 255) bsum[blockIdx.x] = sh[255];
}

// ------- scan23 -------

__global__ void scan23(int* __restrict__ rowp, const int* __restrict__ bsum,
                       int nb, int n, int E) {
  __shared__ int sh[512];
  int t = threadIdx.x;
  sh[t] = (t < nb) ? bsum[t] : 0;
  __syncthreads();
  for (int off = 1; off < 512; off <<= 1) {
    int u = (t >= off) ? sh[t - off] : 0;
    __syncthreads();
    sh[t] += u;
    __syncthreads();
  }
  #pragma unroll
  for (int k = 0; k < 2; k++) {
    int i = blockIdx.x * 1024 + k * 512 + t;
    if (i < n) {
      int j = i >> 8;
      int add = j ? sh[j - 1] : 0;
      rowp[i] += add;
    }
  }
  if (blockIdx.x == 0 && t == 0) rowp[n] = E;
}

// ------- fill (atomic-free scatter) + prescale-to-int8, one dispatch -------
// prescale: group of 16 lanes per row; S = quant8(dinv*x), per-row scale cs.

__global__ void fill_prescale(const int* __restrict__ src, const int* __restrict__ dst,
                              const int* __restrict__ rank, const int* __restrict__ rowp,
                              int* __restrict__ col, int E,
                              const float* __restrict__ x, const float* __restrict__ dinv,
                              uint2* __restrict__ S, float* __restrict__ cs, int n, int fb) {
  int b = blockIdx.x, t = threadIdx.x;
  if (b < fb) {
    int i0 = b * 2048 + t;
    #pragma unroll
    for (int j = 0; j < 8; j++) {
      int e = i0 + j * 256;
      if (e < E) col[rowp[dst[e]] + rank[e]] = src[e];
    }
  } else {
    int idx = (b - fb) * 16 + (t >> 4);
    int l = t & 15;
    int ridx = min(idx, n - 1);
    float d = dinv[ridx];
    float4 f0 = ((const float4*)x)[(size_t)ridx * 32 + l * 2];
    float4 f1 = ((const float4*)x)[(size_t)ridx * 32 + l * 2 + 1];
    float v0 = f0.x * d, v1 = f0.y * d, v2 = f0.z * d, v3 = f0.w * d;
    float v4 = f1.x * d, v5 = f1.y * d, v6 = f1.z * d, v7 = f1.w * d;
    float mx = fmaxf(fmaxf(fmaxf(fabsf(v0), fabsf(v1)), fmaxf(fabsf(v2), fabsf(v3))),
                     fmaxf(fmaxf(fabsf(v4), fabsf(v5)), fmaxf(fabsf(v6), fabsf(v7))));
    mx = fmaxf(mx, __shfl_xor(mx, 1));
    mx = fmaxf(mx, __shfl_xor(mx, 2));
    mx = fmaxf(mx, __shfl_xor(mx, 4));
    mx = fmaxf(mx, __shfl_xor(mx, 8));
    float c = mx * (1.0f / 127.0f);
    float rinv = (mx > 0.f) ? 127.0f / mx : 0.f;
    if (idx < n) {
      unsigned lo = qb(v0, rinv) | (qb(v1, rinv) << 8) | (qb(v2, rinv) << 16) | (qb(v3, rinv) << 24);
      unsigned hi = qb(v4, rinv) | (qb(v5, rinv) << 8) | (qb(v6, rinv) << 16) | (qb(v7, rinv) << 24);
      S[(size_t)idx * 16 + l] = make_uint2(lo, hi);
      if (l == 0) cs[idx] = c;
    }
  }
}

// ------- aggregation (int8 state, per-row scale; 16-lane groups) -------
// out_i(bf16) = dinv_i * (c_i q_i + sum_{j->i} c_j q_j)

__device__ __forceinline__ void acc8(uint2 v, float c, float* a) {
  int xx = (int)v.x, yy = (int)v.y;
  a[0] += c * (float)(signed char)(xx);
  a[1] += c * (float)(signed char)(xx >> 8);
  a[2] += c * (float)(signed char)(xx >> 16);
  a[3] += c * (float)(xx >> 24);
  a[4] += c * (float)(signed char)(yy);
  a[5] += c * (float)(signed char)(yy >> 8);
  a[6] += c * (float)(signed char)(yy >> 16);
  a[7] += c * (float)(yy >> 24);
}

__global__ void agg_i8(const uint2* __restrict__ S, const float* __restrict__ cs,
                       const float* __restrict__ dinv,
                       const int* __restrict__ rowp, const int* __restrict__ col,
                       uint4* __restrict__ OUT, int n) {
  int g = (blockIdx.x * blockDim.x + threadIdx.x) >> 4;
  int lane = threadIdx.x & 15;
  if (g >= n) return;
  float a[8];
  {
    uint2 q = S[(size_t)g * 16 + lane];
    float c = cs[g];
    int xx = (int)q.x, yy = (int)q.y;
    a[0] = c * (float)(signed char)(xx);
    a[1] = c * (float)(signed char)(xx >> 8);
    a[2] = c * (float)(signed char)(xx >> 16);
    a[3] = c * (float)(xx >> 24);
    a[4] = c * (float)(signed char)(yy);
    a[5] = c * (float)(signed char)(yy >> 8);
    a[6] = c * (float)(signed char)(yy >> 16);
    a[7] = c * (float)(yy >> 24);
  }
  int e0 = rowp[g], e1 = rowp[g + 1];
  int e = e0;
  for (; e + 3 < e1; e += 4) {
    int s0 = col[e], s1 = col[e + 1], s2 = col[e + 2], s3 = col[e + 3];
    uint2 q0 = S[(size_t)s0 * 16 + lane];
    uint2 q1 = S[(size_t)s1 * 16 + lane];
    uint2 q2 = S[(size_t)s2 * 16 + lane];
    uint2 q3 = S[(size_t)s3 * 16 + lane];
    float c0 = cs[s0], c1 = cs[s1], c2 = cs[s2], c3 = cs[s3];
    acc8(q0, c0, a); acc8(q1, c1, a); acc8(q2, c2, a); acc8(q3, c3, a);
  }
  for (; e < e1; e++) {
    int s = col[e];
    uint2 q = S[(size_t)s * 16 + lane];
    acc8(q, cs[s], a);
  }
  float d = dinv[g];
  uint4 o;
  o.x = pk2(a[0] * d, a[1] * d); o.y = pk2(a[2] * d, a[3] * d);
  o.z = pk2(a[4] * d, a[5] * d); o.w = pk2(a[6] * d, a[7] * d);
  OUT[(size_t)g * 16 + lane] = o;
}

// ------- MFMA GEMM -> int8 quantized state (layers 0,1) -------
// state = quant8(dinv * relu(A@W + b)), per-row scale.

__global__ __launch_bounds__(256) void gemm_mfma_q8(
    const uint4* __restrict__ A, const uint4* __restrict__ WThi, const uint4* __restrict__ WTlo,
    const float* __restrict__ bias, const float* __restrict__ dinv,
    unsigned char* __restrict__ Sout, float* __restrict__ csout, int n) {
  __shared__ char Lq[64 * 128];
  __shared__ float Lc[64];
  int t = threadIdx.x;
  int lane = t & 63, wv = t >> 6;
  int m = lane & 15, quad = lane >> 4;
  int block0 = blockIdx.x * 64;
  int row0 = block0 + wv * 16;
  int arow = row0 + m;
  f32x4 acc[8];
  #pragma unroll
  for (int i = 0; i < 8; i++) acc[i] = (f32x4){0.f, 0.f, 0.f, 0.f};
  #pragma unroll
  for (int kb = 0; kb < 4; kb++) {
    uint4 av = (arow < n) ? A[(size_t)arow * 16 + kb * 4 + quad] : make_uint4(0, 0, 0, 0);
    short8 af = __builtin_bit_cast(short8, av);
    #pragma unroll
    for (int nt = 0; nt < 8; nt++) {
      int colr = nt * 16 + m;
      uint4 bh = WThi[(size_t)colr * 16 + kb * 4 + quad];
      uint4 bl = WTlo[(size_t)colr * 16 + kb * 4 + quad];
      acc[nt] = __builtin_amdgcn_mfma_f32_16x16x32_bf16(af, __builtin_bit_cast(short8, bh), acc[nt], 0, 0, 0);
      acc[nt] = __builtin_amdgcn_mfma_f32_16x16x32_bf16(af, __builtin_bit_cast(short8, bl), acc[nt], 0, 0, 0);
    }
  }
  #pragma unroll
  for (int r = 0; r < 4; r++) {
    int lrow = wv * 16 + quad * 4 + r;
    int grow = block0 + lrow;
    float sc = (grow < n) ? dinv[grow] : 0.f;
    float v[8];
    float mx = 0.f;
    #pragma unroll
    for (int nt = 0; nt < 8; nt++) {
      v[nt] = fmaxf(acc[nt][r] + bias[nt * 16 + m], 0.f) * sc;  // >= 0 after relu
      mx = fmaxf(mx, v[nt]);
    }
    mx = fmaxf(mx, __shfl_xor(mx, 1));
    mx = fmaxf(mx, __shfl_xor(mx, 2));
    mx = fmaxf(mx, __shfl_xor(mx, 4));
    mx = fmaxf(mx, __shfl_xor(mx, 8));
    float c = mx * (1.0f / 127.0f);
    float rinv = (mx > 0.f) ? 127.0f / mx : 0.f;
    #pragma unroll
    for (int nt = 0; nt < 8; nt++) {
      Lq[lrow * 128 + nt * 16 + m] = (char)(int)rintf(v[nt] * rinv);
    }
    if (m == 0) Lc[lrow] = c;
  }
  __syncthreads();
  for (int i = t; i < 512; i += 256) {
    int lrow = i >> 3, seg = i & 7;
    int grow = block0 + lrow;
    if (grow < n)
      ((uint4*)Sout)[(size_t)grow * 8 + seg] = *(const uint4*)&Lq[lrow * 128 + seg * 16];
  }
  if (t < 64 && block0 + t < n) csout[block0 + t] = Lc[t];
}

// ------- MFMA GEMM -> bf16 out (final layer) -------

__global__ __launch_bounds__(256) void gemm_mfma(
    const uint4* __restrict__ A, const uint4* __restrict__ WThi, const uint4* __restrict__ WTlo,
    const float* __restrict__ bias, unsigned short* __restrict__ Y, int n) {
  int t = threadIdx.x;
  int lane = t & 63, wv = t >> 6;
  int m = lane & 15, quad = lane >> 4;
  int row0 = blockIdx.x * 64 + wv * 16;
  int arow = row0 + m;
  f32x4 acc[8];
  #pragma unroll
  for (int i = 0; i < 8; i++) acc[i] = (f32x4){0.f, 0.f, 0.f, 0.f};
  #pragma unroll
  for (int kb = 0; kb < 4; kb++) {
    uint4 av = (arow < n) ? A[(size_t)arow * 16 + kb * 4 + quad] : make_uint4(0, 0, 0, 0);
    short8 af = __builtin_bit_cast(short8, av);
    #pragma unroll
    for (int nt = 0; nt < 8; nt++) {
      int colr = nt * 16 + m;
      uint4 bh = WThi[(size_t)colr * 16 + kb * 4 + quad];
      uint4 bl = WTlo[(size_t)colr * 16 + kb * 4 + quad];
      acc[nt] = __builtin_amdgcn_mfma_f32_16x16x32_bf16(af, __builtin_bit_cast(short8, bh), acc[nt], 0, 0, 0);
      acc[nt] = __builtin_amdgcn_mfma_f32_16x16x32_bf16(af, __builtin_bit_cast(short8, bl), acc[nt], 0, 0, 0);
    }
  }
  #pragma unroll
  for (int r = 0; r < 4; r++) {
    int grow = row0 + quad * 4 + r;
    if (grow < n) {
      #pragma unroll
      for (int nt = 0; nt < 8; nt++) {
        int colr = nt * 16 + m;
        float v = fmaxf(acc[nt][r] + bias[colr], 0.f);
        Y[(size_t)grow * 128 + colr] = f2bf(v);
      }
    }
  }
}

// ------- mean pool (batch sorted, bf16 input; parallel) -------

__global__ void pool_kernel(const unsigned short* __restrict__ X, const int* __restrict__ batch,
                            float* __restrict__ pooled, float* __restrict__ gcnt, int n) {
  int t = threadIdx.x;             // 128 threads = columns
  int r0 = blockIdx.x * 64;
  if (r0 >= n) return;
  int r1 = min(r0 + 64, n);
  int g = batch[r0];
  float acc = 0.f, cl = 0.f;
  for (int r = r0; r < r1; r++) {
    int gr = batch[r];
    if (gr != g) {
      atomicAdd(&pooled[g * HDIM + t], acc);
      if (t == 0) atomicAdd(&gcnt[g], cl);
      acc = 0.f; cl = 0.f; g = gr;
    }
    acc += __uint_as_float((unsigned)X[(size_t)r * HDIM + t] << 16);
    cl += 1.f;
  }
  atomicAdd(&pooled[g * HDIM + t], acc);
  if (t == 0) atomicAdd(&gcnt[g], cl);
}

// ------- classifier head -------

__global__ void cls_kernel(const float* __restrict__ pooled, const float* __restrict__ gcnt,
                           const float* __restrict__ Wc1, const float* __restrict__ bc1,
                           const float* __restrict__ Wc2, const float* __restrict__ bc2,
                           float* __restrict__ out) {
  __shared__ float p[HDIM];
  __shared__ float r0s[HDIM], r1s[HDIM];
  int g = blockIdx.x, t = threadIdx.x;
  float c = fmaxf(gcnt[g], 1.0f);
  p[t] = pooled[g * HDIM + t] / c;
  __syncthreads();
  float acc = bc1[t];
  for (int k = 0; k < HDIM; k++) {
    acc += p[k] * (Wc1[k * HDIM + t] + Wc1[(HDIM + k) * HDIM + t]);
  }
  float h = fmaxf(acc, 0.f);
  r0s[t] = h * Wc2[t * 2 + 0];
  r1s[t] = h * Wc2[t * 2 + 1];
  __syncthreads();
  for (int s2 = 64; s2 > 0; s2 >>= 1) {
    if (t < s2) { r0s[t] += r0s[t + s2]; r1s[t] += r1s[t + s2]; }
    __syncthreads();
  }
  if (t == 0) {
    out[g * 2 + 0] = r0s[0] + bc2[0];
    out[g * 2 + 1] = r1s[0] + bc2[1];
  }
}

// ------- launch -------

extern "C" void kernel_launch(void* const* d_in, const int* in_sizes, int n_in,
                              void* d_out, int out_size, void* d_ws, size_t ws_size,
                              hipStream_t stream) {
  const float* x   = (const float*)d_in[0];
  const int*   ei  = (const int*)d_in[1];
  const int*   bat = (const int*)d_in[2];
  const float* W0  = (const float*)d_in[3];
  const float* b0  = (const float*)d_in[4];
  const float* W1  = (const float*)d_in[5];
  const float* b1  = (const float*)d_in[6];
  const float* W2  = (const float*)d_in[7];
  const float* b2  = (const float*)d_in[8];
  const float* Wc1 = (const float*)d_in[9];
  const float* bc1 = (const float*)d_in[10];
  const float* Wc2 = (const float*)d_in[11];
  const float* bc2 = (const float*)d_in[12];
  float* out = (float*)d_out;

  int N = in_sizes[0] / HDIM;
  int E = in_sizes[1] / 2;
  const int* src = ei;
  const int* dst = ei + E;

  char* ws = (char*)d_ws;
  size_t off = 0;
  auto alloc = [&](size_t bytes) -> void* {
    void* p = (void*)(ws + off);
    off += (bytes + 511) & ~(size_t)511;
    return p;
  };
  // state region: Sa (int8) | Sb (int8); final bf16 H aliases the whole region
  unsigned char* Sa = (unsigned char*)alloc((size_t)N * HDIM * 2);
  unsigned char* Sb = Sa + (size_t)N * HDIM;
  unsigned short* H = (unsigned short*)Sa;
  unsigned short* Abuf = (unsigned short*)alloc((size_t)N * HDIM * 2);  // agg out bf16
  float* csa  = (float*)alloc((size_t)N * 4);
  float* csb  = (float*)alloc((size_t)N * 4);
  float* dinv = (float*)alloc((size_t)N * 4);
  int*   cnt  = (int*)alloc((size_t)N * 4);
  int*   rowp = (int*)alloc((size_t)(N + 1) * 4);
  int*   col  = (int*)alloc((size_t)E * 4);
  int*   rank = (int*)alloc((size_t)E * 4);
  float* pooled = (float*)alloc((size_t)GCOUNT * HDIM * 4);
  float* gcnt   = (float*)alloc((size_t)GCOUNT * 4);
  unsigned short* wt_hi[3], *wt_lo[3];
  for (int i = 0; i < 3; i++) {
    wt_hi[i] = (unsigned short*)alloc(HDIM * HDIM * 2);
    wt_lo[i] = (unsigned short*)alloc(HDIM * HDIM * 2);
  }
  int nb = (N + 255) / 256;
  int* bsum = (int*)alloc((size_t)nb * 4);

  // 1. setup: zero cnt/pooled/gcnt + weight transposes
  int pz = (GCOUNT * HDIM + GCOUNT + 255) / 256;
  setup_kernel<<<192 + nb + pz, 256, 0, stream>>>(W0, W1, W2, wt_hi[0], wt_lo[0],
      wt_hi[1], wt_lo[1], wt_hi[2], wt_lo[2], cnt, N, pooled, gcnt, nb);

  // 2. histogram (+rank)
  int eb4 = (E + 1023) / 1024;
  hist_kernel<<<eb4, 256, 0, stream>>>(dst, cnt, rank, E);

  // 3-4. scans (+dinv)
  scan1<<<nb, 256, 0, stream>>>(cnt, rowp, bsum, dinv, N);
  scan23<<<(N + 1023) / 1024, 512, 0, stream>>>(rowp, bsum, nb, N, E);

  // 5. fill CSR + prescale state (int8)
  int eb8 = (E + 2047) / 2048;
  int psb = (N + 15) / 16;
  fill_prescale<<<eb8 + psb, 256, 0, stream>>>(src, dst, rank, rowp, col, E,
      x, dinv, (uint2*)Sa, csa, N, eb8);

  // 6-12. agg (int8 gather) + MFMA gemm (quantizing epilogue), ping-pong
  int aggBlocks = (N + 15) / 16;
  int gemmBlocks = (N + 63) / 64;

  agg_i8<<<aggBlocks, 256, 0, stream>>>((const uint2*)Sa, csa, dinv, rowp, col, (uint4*)Abuf, N);
  gemm_mfma_q8<<<gemmBlocks, 256, 0, stream>>>((const uint4*)Abuf, (const uint4*)wt_hi[0],
      (const uint4*)wt_lo[0], b0, dinv, Sb, csb, N);

  agg_i8<<<aggBlocks, 256, 0, stream>>>((const uint2*)Sb, csb, dinv, rowp, col, (uint4*)Abuf, N);
  gemm_mfma_q8<<<gemmBlocks, 256, 0, stream>>>((const uint4*)Abuf, (const uint4*)wt_hi[1],
      (const uint4*)wt_lo[1], b1, dinv, Sa, csa, N);

  agg_i8<<<aggBlocks, 256, 0, stream>>>((const uint2*)Sa, csa, dinv, rowp, col, (uint4*)Abuf, N);
  gemm_mfma<<<gemmBlocks, 256, 0, stream>>>((const uint4*)Abuf, (const uint4*)wt_hi[2],
      (const uint4*)wt_lo[2], b2, H, N);

  // 13-14. parallel pool + classifier
  pool_kernel<<<(N + 63) / 64, 128, 0, stream>>>(H, bat, pooled, gcnt, N);
  cls_kernel<<<GCOUNT, HDIM, 0, stream>>>(pooled, gcnt, Wc1, bc1, Wc2, bc2, out);
}

// Round 10
// 488.001 us; speedup vs baseline: 1.2964x; 1.1192x over previous
//
#include <hip/hip_runtime.h>

#define HDIM 128
#define GCOUNT 64
#define CHUNK 8192

// ---- bf16 helpers (manual, RNE) ----
__device__ __forceinline__ float bfl(unsigned u) { return __uint_as_float(u << 16); }
__device__ __forceinline__ float bfh(unsigned u) { return __uint_as_float(u & 0xffff0000u); }
__device__ __forceinline__ unsigned short f2bf(float f) {
  unsigned u = __float_as_uint(f);
  unsigned r = (u + 0x7fffu + ((u >> 16) & 1u)) >> 16;
  return (unsigned short)r;
}
__device__ __forceinline__ unsigned pk2(float a, float b) {
  return (unsigned)f2bf(a) | ((unsigned)f2bf(b) << 16);
}

typedef __attribute__((ext_vector_type(8))) short short8;
typedef __attribute__((ext_vector_type(4))) float f32x4;

__device__ __forceinline__ unsigned qb(float v, float rinv) {
  int q = (int)rintf(v * rinv);
  return (unsigned)(q & 0xff);
}

// ------- mega1: weight transpose | zero pooled/gcnt | coarse hist | prescale int8 -------

__global__ void mega1(const float* __restrict__ W0, const float* __restrict__ W1,
                      const float* __restrict__ W2,
                      unsigned short* __restrict__ h0, unsigned short* __restrict__ l0,
                      unsigned short* __restrict__ h1, unsigned short* __restrict__ l1,
                      unsigned short* __restrict__ h2, unsigned short* __restrict__ l2,
                      float* __restrict__ pooled, float* __restrict__ gcnt, int pz,
                      const int* __restrict__ dst, int E, int G, int NB1,
                      int* __restrict__ gcount,
                      const float* __restrict__ x, uint2* __restrict__ S,
                      float* __restrict__ cs_base, int n) {
  __shared__ int hist[512];
  int b = blockIdx.x, t = threadIdx.x;
  if (b < 192) {
    int w = b >> 6;
    int idx = (b & 63) * 256 + t;
    const float* W = (w == 0) ? W0 : (w == 1) ? W1 : W2;
    unsigned short* hi = (w == 0) ? h0 : (w == 1) ? h1 : h2;
    unsigned short* lo = (w == 0) ? l0 : (w == 1) ? l1 : l2;
    int k = idx >> 7, nn = idx & 127;
    float wv = W[idx];
    unsigned short h = f2bf(wv);
    float hf = __uint_as_float((unsigned)h << 16);
    unsigned short l = f2bf(wv - hf);
    hi[nn * 128 + k] = h;
    lo[nn * 128 + k] = l;
  } else if (b < 192 + pz) {
    int i = (b - 192) * 256 + t;
    if (i < GCOUNT * HDIM) pooled[i] = 0.f;
    else if (i - GCOUNT * HDIM < GCOUNT) gcnt[i - GCOUNT * HDIM] = 0.f;
  } else if (b < 192 + pz + G) {
    int blk = b - 192 - pz;
    for (int i = t; i < NB1; i += 256) hist[i] = 0;
    __syncthreads();
    int base = blk * CHUNK;
    for (int i = t; i < CHUNK; i += 256) {
      int e = base + i;
      if (e < E) atomicAdd(&hist[dst[e] >> 8], 1);
    }
    __syncthreads();
    for (int i = t; i < NB1; i += 256) gcount[i * G + blk] = hist[i];
  } else {
    // prescale WITHOUT dinv: q = round(127*x/rowmax), cs_base = rowmax/127
    int idx = (b - 192 - pz - G) * 16 + (t >> 4);
    int l = t & 15;
    int ridx = min(idx, n - 1);
    float4 f0 = ((const float4*)x)[(size_t)ridx * 32 + l * 2];
    float4 f1 = ((const float4*)x)[(size_t)ridx * 32 + l * 2 + 1];
    float v0 = f0.x, v1 = f0.y, v2 = f0.z, v3 = f0.w;
    float v4 = f1.x, v5 = f1.y, v6 = f1.z, v7 = f1.w;
    float mx = fmaxf(fmaxf(fmaxf(fabsf(v0), fabsf(v1)), fmaxf(fabsf(v2), fabsf(v3))),
                     fmaxf(fmaxf(fabsf(v4), fabsf(v5)), fmaxf(fabsf(v6), fabsf(v7))));
    mx = fmaxf(mx, __shfl_xor(mx, 1));
    mx = fmaxf(mx, __shfl_xor(mx, 2));
    mx = fmaxf(mx, __shfl_xor(mx, 4));
    mx = fmaxf(mx, __shfl_xor(mx, 8));
    float c = mx * (1.0f / 127.0f);
    float rinv = (mx > 0.f) ? 127.0f / mx : 0.f;
    if (idx < n) {
      unsigned lo = qb(v0, rinv) | (qb(v1, rinv) << 8) | (qb(v2, rinv) << 16) | (qb(v3, rinv) << 24);
      unsigned hi = qb(v4, rinv) | (qb(v5, rinv) << 8) | (qb(v6, rinv) << 16) | (qb(v7, rinv) << 24);
      S[(size_t)idx * 16 + l] = make_uint2(lo, hi);
      if (l == 0) cs_base[idx] = c;
    }
  }
}

// ------- scanA: per-256-block exclusive scan (in-place safe) -------

__global__ void scanA(int* __restrict__ g, int* __restrict__ bsum, int M) {
  __shared__ int sh[256];
  int t = threadIdx.x;
  int i = blockIdx.x * 256 + t;
  int v = (i < M) ? g[i] : 0;
  sh[t] = v;
  __syncthreads();
  for (int off = 1; off < 256; off <<= 1) {
    int u = (t >= off) ? sh[t - off] : 0;
    __syncthreads();
    sh[t] += u;
    __syncthreads();
  }
  if (i < M) g[i] = sh[t] - v;
  if (t == 255) bsum[blockIdx.x] = sh[255];
}

// ------- scanB: each block redundantly scans bsum (nb<=512), applies offsets -------

__global__ void scanB(int* __restrict__ g, const int* __restrict__ bsum, int nb, int M) {
  __shared__ int sh[512];
  int t = threadIdx.x;
  sh[t] = (t < nb) ? bsum[t] : 0;
  __syncthreads();
  for (int off = 1; off < 512; off <<= 1) {
    int u = (t >= off) ? sh[t - off] : 0;
    __syncthreads();
    sh[t] += u;
    __syncthreads();
  }
  #pragma unroll
  for (int k = 0; k < 2; k++) {
    int i = blockIdx.x * 1024 + k * 512 + t;
    if (i < M) {
      int j = i >> 8;
      if (j) g[i] += sh[j - 1];
    }
  }
}

// ------- rs_scatter: group (dst,src) pairs by coarse bucket (dst>>8), LDS atomics only ----

__global__ void rs_scatter(const int* __restrict__ src, const int* __restrict__ dst,
                           const int* __restrict__ gscan, int E, int G, int NB1,
                           uint2* __restrict__ sp) {
  __shared__ int run[512];
  int blk = blockIdx.x, t = threadIdx.x;
  for (int i = t; i < NB1; i += 256) run[i] = gscan[i * G + blk];
  __syncthreads();
  int base = blk * CHUNK;
  for (int i = t; i < CHUNK; i += 256) {
    int e = base + i;
    if (e < E) {
      int d = dst[e];
      int pos = atomicAdd(&run[d >> 8], 1);
      sp[pos] = make_uint2((unsigned)d, (unsigned)src[e]);
    }
  }
}

// ------- csr_fine: one block per coarse bucket; builds rowp/col/dinv/cs, LDS only ----

__global__ void csr_fine(const uint2* __restrict__ sp, const int* __restrict__ gscan,
                         int E, int G, int NB1,
                         int* __restrict__ rowp, int* __restrict__ colv,
                         float* __restrict__ dinv, const float* __restrict__ cs_base,
                         float* __restrict__ cs, int n) {
  __shared__ int hist[256];
  __shared__ int scn[256];
  __shared__ int run2[256];
  int hb = blockIdx.x, t = threadIdx.x;
  int O = gscan[hb * G];
  int Oe = (hb == NB1 - 1) ? E : gscan[(hb + 1) * G];
  hist[t] = 0;
  __syncthreads();
  for (int e = O + t; e < Oe; e += 256) atomicAdd(&hist[sp[e].x & 255], 1);
  __syncthreads();
  int v = hist[t];
  scn[t] = v;
  __syncthreads();
  for (int off = 1; off < 256; off <<= 1) {
    int u = (t >= off) ? scn[t - off] : 0;
    __syncthreads();
    scn[t] += u;
    __syncthreads();
  }
  int excl = scn[t] - v;
  run2[t] = O + excl;
  int d = (hb << 8) + t;
  rowp[d] = O + excl;
  if (d < n) {
    float dv = rsqrtf((float)v + 1.0f);
    dinv[d] = dv;
    cs[d] = cs_base[d] * dv;
  }
  if (hb == NB1 - 1 && t == 0) rowp[n] = E;   // also covered by excl path when n&255!=0
  __syncthreads();
  for (int e = O + t; e < Oe; e += 256) {
    uint2 p = sp[e];
    int pos = atomicAdd(&run2[p.x & 255], 1);
    colv[pos] = (int)p.y;
  }
}

// ------- aggregation (int8 state, per-row scale; 16-lane groups) -------

__device__ __forceinline__ void acc8(uint2 v, float c, float* a) {
  int xx = (int)v.x, yy = (int)v.y;
  a[0] += c * (float)(signed char)(xx);
  a[1] += c * (float)(signed char)(xx >> 8);
  a[2] += c * (float)(signed char)(xx >> 16);
  a[3] += c * (float)(xx >> 24);
  a[4] += c * (float)(signed char)(yy);
  a[5] += c * (float)(signed char)(yy >> 8);
  a[6] += c * (float)(signed char)(yy >> 16);
  a[7] += c * (float)(yy >> 24);
}

__global__ void agg_i8(const uint2* __restrict__ S, const float* __restrict__ cs,
                       const float* __restrict__ dinv,
                       const int* __restrict__ rowp, const int* __restrict__ col,
                       uint4* __restrict__ OUT, int n) {
  int g = (blockIdx.x * blockDim.x + threadIdx.x) >> 4;
  int lane = threadIdx.x & 15;
  if (g >= n) return;
  float a[8];
  {
    uint2 q = S[(size_t)g * 16 + lane];
    float c = cs[g];
    int xx = (int)q.x, yy = (int)q.y;
    a[0] = c * (float)(signed char)(xx);
    a[1] = c * (float)(signed char)(xx >> 8);
    a[2] = c * (float)(signed char)(xx >> 16);
    a[3] = c * (float)(xx >> 24);
    a[4] = c * (float)(signed char)(yy);
    a[5] = c * (float)(signed char)(yy >> 8);
    a[6] = c * (float)(signed char)(yy >> 16);
    a[7] = c * (float)(yy >> 24);
  }
  int e0 = rowp[g], e1 = rowp[g + 1];
  int e = e0;
  for (; e + 3 < e1; e += 4) {
    int s0 = col[e], s1 = col[e + 1], s2 = col[e + 2], s3 = col[e + 3];
    uint2 q0 = S[(size_t)s0 * 16 + lane];
    uint2 q1 = S[(size_t)s1 * 16 + lane];
    uint2 q2 = S[(size_t)s2 * 16 + lane];
    uint2 q3 = S[(size_t)s3 * 16 + lane];
    float c0 = cs[s0], c1 = cs[s1], c2 = cs[s2], c3 = cs[s3];
    acc8(q0, c0, a); acc8(q1, c1, a); acc8(q2, c2, a); acc8(q3, c3, a);
  }
  for (; e < e1; e++) {
    int s = col[e];
    uint2 q = S[(size_t)s * 16 + lane];
    acc8(q, cs[s], a);
  }
  float d = dinv[g];
  uint4 o;
  o.x = pk2(a[0] * d, a[1] * d); o.y = pk2(a[2] * d, a[3] * d);
  o.z = pk2(a[4] * d, a[5] * d); o.w = pk2(a[6] * d, a[7] * d);
  OUT[(size_t)g * 16 + lane] = o;
}

// ------- MFMA GEMM -> int8 quantized state (layers 0,1) -------

__global__ __launch_bounds__(256) void gemm_mfma_q8(
    const uint4* __restrict__ A, const uint4* __restrict__ WThi, const uint4* __restrict__ WTlo,
    const float* __restrict__ bias, const float* __restrict__ dinv,
    unsigned char* __restrict__ Sout, float* __restrict__ csout, int n) {
  __shared__ char Lq[64 * 128];
  __shared__ float Lc[64];
  int t = threadIdx.x;
  int lane = t & 63, wv = t >> 6;
  int m = lane & 15, quad = lane >> 4;
  int block0 = blockIdx.x * 64;
  int row0 = block0 + wv * 16;
  int arow = row0 + m;
  f32x4 acc[8];
  #pragma unroll
  for (int i = 0; i < 8; i++) acc[i] = (f32x4){0.f, 0.f, 0.f, 0.f};
  #pragma unroll
  for (int kb = 0; kb < 4; kb++) {
    uint4 av = (arow < n) ? A[(size_t)arow * 16 + kb * 4 + quad] : make_uint4(0, 0, 0, 0);
    short8 af = __builtin_bit_cast(short8, av);
    #pragma unroll
    for (int nt = 0; nt < 8; nt++) {
      int colr = nt * 16 + m;
      uint4 bh = WThi[(size_t)colr * 16 + kb * 4 + quad];
      uint4 bl = WTlo[(size_t)colr * 16 + kb * 4 + quad];
      acc[nt] = __builtin_amdgcn_mfma_f32_16x16x32_bf16(af, __builtin_bit_cast(short8, bh), acc[nt], 0, 0, 0);
      acc[nt] = __builtin_amdgcn_mfma_f32_16x16x32_bf16(af, __builtin_bit_cast(short8, bl), acc[nt], 0, 0, 0);
    }
  }
  #pragma unroll
  for (int r = 0; r < 4; r++) {
    int lrow = wv * 16 + quad * 4 + r;
    int grow = block0 + lrow;
    float sc = (grow < n) ? dinv[grow] : 0.f;
    float v[8];
    float mx = 0.f;
    #pragma unroll
    for (int nt = 0; nt < 8; nt++) {
      v[nt] = fmaxf(acc[nt][r] + bias[nt * 16 + m], 0.f) * sc;
      mx = fmaxf(mx, v[nt]);
    }
    mx = fmaxf(mx, __shfl_xor(mx, 1));
    mx = fmaxf(mx, __shfl_xor(mx, 2));
    mx = fmaxf(mx, __shfl_xor(mx, 4));
    mx = fmaxf(mx, __shfl_xor(mx, 8));
    float c = mx * (1.0f / 127.0f);
    float rinv = (mx > 0.f) ? 127.0f / mx : 0.f;
    #pragma unroll
    for (int nt = 0; nt < 8; nt++) {
      Lq[lrow * 128 + nt * 16 + m] = (char)(int)rintf(v[nt] * rinv);
    }
    if (m == 0) Lc[lrow] = c;
  }
  __syncthreads();
  for (int i = t; i < 512; i += 256) {
    int lrow = i >> 3, seg = i & 7;
    int grow = block0 + lrow;
    if (grow < n)
      ((uint4*)Sout)[(size_t)grow * 8 + seg] = *(const uint4*)&Lq[lrow * 128 + seg * 16];
  }
  if (t < 64 && block0 + t < n) csout[block0 + t] = Lc[t];
}

// ------- MFMA GEMM -> bf16 out (final layer) -------

__global__ __launch_bounds__(256) void gemm_mfma(
    const uint4* __restrict__ A, const uint4* __restrict__ WThi, const uint4* __restrict__ WTlo,
    const float* __restrict__ bias, unsigned short* __restrict__ Y, int n) {
  int t = threadIdx.x;
  int lane = t & 63, wv = t >> 6;
  int m = lane & 15, quad = lane >> 4;
  int row0 = blockIdx.x * 64 + wv * 16;
  int arow = row0 + m;
  f32x4 acc[8];
  #pragma unroll
  for (int i = 0; i < 8; i++) acc[i] = (f32x4){0.f, 0.f, 0.f, 0.f};
  #pragma unroll
  for (int kb = 0; kb < 4; kb++) {
    uint4 av = (arow < n) ? A[(size_t)arow * 16 + kb * 4 + quad] : make_uint4(0, 0, 0, 0);
    short8 af = __builtin_bit_cast(short8, av);
    #pragma unroll
    for (int nt = 0; nt < 8; nt++) {
      int colr = nt * 16 + m;
      uint4 bh = WThi[(size_t)colr * 16 + kb * 4 + quad];
      uint4 bl = WTlo[(size_t)colr * 16 + kb * 4 + quad];
      acc[nt] = __builtin_amdgcn_mfma_f32_16x16x32_bf16(af, __builtin_bit_cast(short8, bh), acc[nt], 0, 0, 0);
      acc[nt] = __builtin_amdgcn_mfma_f32_16x16x32_bf16(af, __builtin_bit_cast(short8, bl), acc[nt], 0, 0, 0);
    }
  }
  #pragma unroll
  for (int r = 0; r < 4; r++) {
    int grow = row0 + quad * 4 + r;
    if (grow < n) {
      #pragma unroll
      for (int nt = 0; nt < 8; nt++) {
        int colr = nt * 16 + m;
        float v = fmaxf(acc[nt][r] + bias[colr], 0.f);
        Y[(size_t)grow * 128 + colr] = f2bf(v);
      }
    }
  }
}

// ------- mean pool (batch sorted, bf16 input; parallel) -------

__global__ void pool_kernel(const unsigned short* __restrict__ X, const int* __restrict__ batch,
                            float* __restrict__ pooled, float* __restrict__ gcnt, int n) {
  int t = threadIdx.x;
  int r0 = blockIdx.x * 64;
  if (r0 >= n) return;
  int r1 = min(r0 + 64, n);
  int g = batch[r0];
  float acc = 0.f, cl = 0.f;
  for (int r = r0; r < r1; r++) {
    int gr = batch[r];
    if (gr != g) {
      atomicAdd(&pooled[g * HDIM + t], acc);
      if (t == 0) atomicAdd(&gcnt[g], cl);
      acc = 0.f; cl = 0.f; g = gr;
    }
    acc += __uint_as_float((unsigned)X[(size_t)r * HDIM + t] << 16);
    cl += 1.f;
  }
  atomicAdd(&pooled[g * HDIM + t], acc);
  if (t == 0) atomicAdd(&gcnt[g], cl);
}

// ------- classifier head -------

__global__ void cls_kernel(const float* __restrict__ pooled, const float* __restrict__ gcnt,
                           const float* __restrict__ Wc1, const float* __restrict__ bc1,
                           const float* __restrict__ Wc2, const float* __restrict__ bc2,
                           float* __restrict__ out) {
  __shared__ float p[HDIM];
  __shared__ float r0s[HDIM], r1s[HDIM];
  int g = blockIdx.x, t = threadIdx.x;
  float c = fmaxf(gcnt[g], 1.0f);
  p[t] = pooled[g * HDIM + t] / c;
  __syncthreads();
  float acc = bc1[t];
  for (int k = 0; k < HDIM; k++) {
    acc += p[k] * (Wc1[k * HDIM + t] + Wc1[(HDIM + k) * HDIM + t]);
  }
  float h = fmaxf(acc, 0.f);
  r0s[t] = h * Wc2[t * 2 + 0];
  r1s[t] = h * Wc2[t * 2 + 1];
  __syncthreads();
  for (int s2 = 64; s2 > 0; s2 >>= 1) {
    if (t < s2) { r0s[t] += r0s[t + s2]; r1s[t] += r1s[t + s2]; }
    __syncthreads();
  }
  if (t == 0) {
    out[g * 2 + 0] = r0s[0] + bc2[0];
    out[g * 2 + 1] = r1s[0] + bc2[1];
  }
}

// ------- launch -------

extern "C" void kernel_launch(void* const* d_in, const int* in_sizes, int n_in,
                              void* d_out, int out_size, void* d_ws, size_t ws_size,
                              hipStream_t stream) {
  const float* x   = (const float*)d_in[0];
  const int*   ei  = (const int*)d_in[1];
  const int*   bat = (const int*)d_in[2];
  const float* W0  = (const float*)d_in[3];
  const float* b0  = (const float*)d_in[4];
  const float* W1  = (const float*)d_in[5];
  const float* b1  = (const float*)d_in[6];
  const float* W2  = (const float*)d_in[7];
  const float* b2  = (const float*)d_in[8];
  const float* Wc1 = (const float*)d_in[9];
  const float* bc1 = (const float*)d_in[10];
  const float* Wc2 = (const float*)d_in[11];
  const float* bc2 = (const float*)d_in[12];
  float* out = (float*)d_out;

  int N = in_sizes[0] / HDIM;
  int E = in_sizes[1] / 2;
  const int* src = ei;
  const int* dst = ei + E;

  int NB1 = (N + 255) >> 8;                 // coarse buckets (dst>>8)
  int G = (E + CHUNK - 1) / CHUNK;          // chunks
  int M = NB1 * G;                          // (bucket,chunk) matrix size

  char* ws = (char*)d_ws;
  size_t off = 0;
  auto alloc = [&](size_t bytes) -> void* {
    void* p = (void*)(ws + off);
    off += (bytes + 511) & ~(size_t)511;
    return p;
  };
  unsigned char* Sa = (unsigned char*)alloc((size_t)N * HDIM * 2);  // int8 ping-pong
  unsigned char* Sb = Sa + (size_t)N * HDIM;
  unsigned short* H = (unsigned short*)Sa;                          // final bf16 aliases
  unsigned short* Abuf = (unsigned short*)alloc((size_t)N * HDIM * 2);
  float* csa  = (float*)alloc((size_t)N * 4);
  float* csb  = (float*)alloc((size_t)N * 4);
  float* cs_base = (float*)alloc((size_t)N * 4);
  float* dinv = (float*)alloc((size_t)N * 4);
  int*   rowp = (int*)alloc((size_t)(NB1 * 256 + 2) * 4);
  int*   colv = (int*)alloc((size_t)E * 4);
  uint2* sp   = (uint2*)alloc((size_t)E * 8);
  float* pooled = (float*)alloc((size_t)GCOUNT * HDIM * 4);
  float* gcnt   = (float*)alloc((size_t)GCOUNT * 4);
  unsigned short* wt_hi[3], *wt_lo[3];
  for (int i = 0; i < 3; i++) {
    wt_hi[i] = (unsigned short*)alloc(HDIM * HDIM * 2);
    wt_lo[i] = (unsigned short*)alloc(HDIM * HDIM * 2);
  }
  int* gcount = (int*)alloc((size_t)(M + 2) * 4);
  int nbM = (M + 255) / 256;
  int* bsum = (int*)alloc((size_t)nbM * 4);

  // 1. mega1: weights | zero pooled/gcnt | coarse hist | prescale (all independent)
  int pz = (GCOUNT * HDIM + GCOUNT + 255) / 256;
  int psb = (N + 15) / 16;
  mega1<<<192 + pz + G + psb, 256, 0, stream>>>(W0, W1, W2,
      wt_hi[0], wt_lo[0], wt_hi[1], wt_lo[1], wt_hi[2], wt_lo[2],
      pooled, gcnt, pz, dst, E, G, NB1, gcount,
      x, (uint2*)Sa, cs_base, N);

  // 2-3. scan of (bucket,chunk) counts
  scanA<<<nbM, 256, 0, stream>>>(gcount, bsum, M);
  scanB<<<(M + 1023) / 1024, 512, 0, stream>>>(gcount, bsum, nbM, M);

  // 4. coarse scatter (LDS atomics only)
  rs_scatter<<<G, 256, 0, stream>>>(src, dst, gcount, E, G, NB1, sp);

  // 5. fine pass: rowp + col + dinv + cs (LDS atomics only)
  csr_fine<<<NB1, 256, 0, stream>>>(sp, gcount, E, G, NB1, rowp, colv,
      dinv, cs_base, csa, N);

  // 6-11. agg (int8 gather) + MFMA gemm (quantizing epilogue), ping-pong
  int aggBlocks = (N + 15) / 16;
  int gemmBlocks = (N + 63) / 64;

  agg_i8<<<aggBlocks, 256, 0, stream>>>((const uint2*)Sa, csa, dinv, rowp, colv, (uint4*)Abuf, N);
  gemm_mfma_q8<<<gemmBlocks, 256, 0, stream>>>((const uint4*)Abuf, (const uint4*)wt_hi[0],
      (const uint4*)wt_lo[0], b0, dinv, Sb, csb, N);

  agg_i8<<<aggBlocks, 256, 0, stream>>>((const uint2*)Sb, csb, dinv, rowp, colv, (uint4*)Abuf, N);
  gemm_mfma_q8<<<gemmBlocks, 256, 0, stream>>>((const uint4*)Abuf, (const uint4*)wt_hi[1],
      (const uint4*)wt_lo[1], b1, dinv, Sa, csa, N);

  agg_i8<<<aggBlocks, 256, 0, stream>>>((const uint2*)Sa, csa, dinv, rowp, colv, (uint4*)Abuf, N);
  gemm_mfma<<<gemmBlocks, 256, 0, stream>>>((const uint4*)Abuf, (const uint4*)wt_hi[2],
      (const uint4*)wt_lo[2], b2, H, N);

  // 12-13. parallel pool + classifier
  pool_kernel<<<(N + 63) / 64, 128, 0, stream>>>(H, bat, pooled, gcnt, N);
  cls_kernel<<<GCOUNT, HDIM, 0, stream>>>(pooled, gcnt, Wc1, bc1, Wc2, bc2, out);
}

// Round 11
// 383.184 us; speedup vs baseline: 1.6511x; 1.2735x over previous
//
#include <hip/hip_runtime.h>

#define HDIM 128
#define GCOUNT 64
#define CHUNK 8192

// ---- bf16 helpers (manual, RNE) ----
__device__ __forceinline__ float bfl(unsigned u) { return __uint_as_float(u << 16); }
__device__ __forceinline__ float bfh(unsigned u) { return __uint_as_float(u & 0xffff0000u); }
__device__ __forceinline__ unsigned short f2bf(float f) {
  unsigned u = __float_as_uint(f);
  unsigned r = (u + 0x7fffu + ((u >> 16) & 1u)) >> 16;
  return (unsigned short)r;
}
__device__ __forceinline__ unsigned pk2(float a, float b) {
  return (unsigned)f2bf(a) | ((unsigned)f2bf(b) << 16);
}

typedef __attribute__((ext_vector_type(8))) short short8;
typedef __attribute__((ext_vector_type(4))) float f32x4;

__device__ __forceinline__ unsigned qb(float v, float rinv) {
  int q = (int)rintf(v * rinv);
  return (unsigned)(q & 0xff);
}

// ------- mega1: weight transpose | zero pooled/gcnt | coarse hist | prescale int8 -------

__global__ void mega1(const float* __restrict__ W0, const float* __restrict__ W1,
                      const float* __restrict__ W2,
                      unsigned short* __restrict__ h0, unsigned short* __restrict__ l0,
                      unsigned short* __restrict__ h1, unsigned short* __restrict__ l1,
                      unsigned short* __restrict__ h2, unsigned short* __restrict__ l2,
                      float* __restrict__ pooled, float* __restrict__ gcnt, int pz,
                      const int* __restrict__ dst, int E, int G, int NB1,
                      int* __restrict__ gcount,
                      const float* __restrict__ x, uint2* __restrict__ S,
                      float* __restrict__ cs_base, int n) {
  __shared__ int hist[512];
  int b = blockIdx.x, t = threadIdx.x;
  if (b < 192) {
    int w = b >> 6;
    int idx = (b & 63) * 256 + t;
    const float* W = (w == 0) ? W0 : (w == 1) ? W1 : W2;
    unsigned short* hi = (w == 0) ? h0 : (w == 1) ? h1 : h2;
    unsigned short* lo = (w == 0) ? l0 : (w == 1) ? l1 : l2;
    int k = idx >> 7, nn = idx & 127;
    float wv = W[idx];
    unsigned short h = f2bf(wv);
    float hf = __uint_as_float((unsigned)h << 16);
    unsigned short l = f2bf(wv - hf);
    hi[nn * 128 + k] = h;
    lo[nn * 128 + k] = l;
  } else if (b < 192 + pz) {
    int i = (b - 192) * 256 + t;
    if (i < GCOUNT * HDIM) pooled[i] = 0.f;
    else if (i - GCOUNT * HDIM < GCOUNT) gcnt[i - GCOUNT * HDIM] = 0.f;
  } else if (b < 192 + pz + G) {
    int blk = b - 192 - pz;
    for (int i = t; i < NB1; i += 256) hist[i] = 0;
    __syncthreads();
    int base = blk * CHUNK;
    for (int i = t; i < CHUNK; i += 256) {
      int e = base + i;
      if (e < E) atomicAdd(&hist[dst[e] >> 8], 1);
    }
    __syncthreads();
    for (int i = t; i < NB1; i += 256) gcount[i * G + blk] = hist[i];
  } else {
    int idx = (b - 192 - pz - G) * 16 + (t >> 4);
    int l = t & 15;
    int ridx = min(idx, n - 1);
    float4 f0 = ((const float4*)x)[(size_t)ridx * 32 + l * 2];
    float4 f1 = ((const float4*)x)[(size_t)ridx * 32 + l * 2 + 1];
    float v0 = f0.x, v1 = f0.y, v2 = f0.z, v3 = f0.w;
    float v4 = f1.x, v5 = f1.y, v6 = f1.z, v7 = f1.w;
    float mx = fmaxf(fmaxf(fmaxf(fabsf(v0), fabsf(v1)), fmaxf(fabsf(v2), fabsf(v3))),
                     fmaxf(fmaxf(fabsf(v4), fabsf(v5)), fmaxf(fabsf(v6), fabsf(v7))));
    mx = fmaxf(mx, __shfl_xor(mx, 1));
    mx = fmaxf(mx, __shfl_xor(mx, 2));
    mx = fmaxf(mx, __shfl_xor(mx, 4));
    mx = fmaxf(mx, __shfl_xor(mx, 8));
    float c = mx * (1.0f / 127.0f);
    float rinv = (mx > 0.f) ? 127.0f / mx : 0.f;
    if (idx < n) {
      unsigned lo = qb(v0, rinv) | (qb(v1, rinv) << 8) | (qb(v2, rinv) << 16) | (qb(v3, rinv) << 24);
      unsigned hi = qb(v4, rinv) | (qb(v5, rinv) << 8) | (qb(v6, rinv) << 16) | (qb(v7, rinv) << 24);
      S[(size_t)idx * 16 + l] = make_uint2(lo, hi);
      if (l == 0) cs_base[idx] = c;
    }
  }
}

// ------- scanA / scanB -------

__global__ void scanA(int* __restrict__ g, int* __restrict__ bsum, int M) {
  __shared__ int sh[256];
  int t = threadIdx.x;
  int i = blockIdx.x * 256 + t;
  int v = (i < M) ? g[i] : 0;
  sh[t] = v;
  __syncthreads();
  for (int off = 1; off < 256; off <<= 1) {
    int u = (t >= off) ? sh[t - off] : 0;
    __syncthreads();
    sh[t] += u;
    __syncthreads();
  }
  if (i < M) g[i] = sh[t] - v;
  if (t == 255) bsum[blockIdx.x] = sh[255];
}

__global__ void scanB(int* __restrict__ g, const int* __restrict__ bsum, int nb, int M) {
  __shared__ int sh[512];
  int t = threadIdx.x;
  sh[t] = (t < nb) ? bsum[t] : 0;
  __syncthreads();
  for (int off = 1; off < 512; off <<= 1) {
    int u = (t >= off) ? sh[t - off] : 0;
    __syncthreads();
    sh[t] += u;
    __syncthreads();
  }
  #pragma unroll
  for (int k = 0; k < 2; k++) {
    int i = blockIdx.x * 1024 + k * 512 + t;
    if (i < M) {
      int j = i >> 8;
      if (j) g[i] += sh[j - 1];
    }
  }
}

// ------- rs_scatter -------

__global__ void rs_scatter(const int* __restrict__ src, const int* __restrict__ dst,
                           const int* __restrict__ gscan, int E, int G, int NB1,
                           uint2* __restrict__ sp) {
  __shared__ int run[512];
  int blk = blockIdx.x, t = threadIdx.x;
  for (int i = t; i < NB1; i += 256) run[i] = gscan[i * G + blk];
  __syncthreads();
  int base = blk * CHUNK;
  for (int i = t; i < CHUNK; i += 256) {
    int e = base + i;
    if (e < E) {
      int d = dst[e];
      int pos = atomicAdd(&run[d >> 8], 1);
      sp[pos] = make_uint2((unsigned)d, (unsigned)src[e]);
    }
  }
}

// ------- csr_fine -------

__global__ void csr_fine(const uint2* __restrict__ sp, const int* __restrict__ gscan,
                         int E, int G, int NB1,
                         int* __restrict__ rowp, int* __restrict__ colv,
                         float* __restrict__ dinv, const float* __restrict__ cs_base,
                         float* __restrict__ cs, int n) {
  __shared__ int hist[256];
  __shared__ int scn[256];
  __shared__ int run2[256];
  int hb = blockIdx.x, t = threadIdx.x;
  int O = gscan[hb * G];
  int Oe = (hb == NB1 - 1) ? E : gscan[(hb + 1) * G];
  hist[t] = 0;
  __syncthreads();
  for (int e = O + t; e < Oe; e += 256) atomicAdd(&hist[sp[e].x & 255], 1);
  __syncthreads();
  int v = hist[t];
  scn[t] = v;
  __syncthreads();
  for (int off = 1; off < 256; off <<= 1) {
    int u = (t >= off) ? scn[t - off] : 0;
    __syncthreads();
    scn[t] += u;
    __syncthreads();
  }
  int excl = scn[t] - v;
  run2[t] = O + excl;
  int d = (hb << 8) + t;
  rowp[d] = O + excl;
  if (d < n) {
    float dv = rsqrtf((float)v + 1.0f);
    dinv[d] = dv;
    cs[d] = cs_base[d] * dv;
  }
  if (hb == NB1 - 1 && t == 0) rowp[n] = E;
  __syncthreads();
  for (int e = O + t; e < Oe; e += 256) {
    uint2 p = sp[e];
    int pos = atomicAdd(&run2[p.x & 255], 1);
    colv[pos] = (int)p.y;
  }
}

// ------- aggregation (int8 state, per-row scale; 16-lane groups) -------

__device__ __forceinline__ void acc8(uint2 v, float c, float* a) {
  int xx = (int)v.x, yy = (int)v.y;
  a[0] += c * (float)(signed char)(xx);
  a[1] += c * (float)(signed char)(xx >> 8);
  a[2] += c * (float)(signed char)(xx >> 16);
  a[3] += c * (float)(xx >> 24);
  a[4] += c * (float)(signed char)(yy);
  a[5] += c * (float)(signed char)(yy >> 8);
  a[6] += c * (float)(signed char)(yy >> 16);
  a[7] += c * (float)(yy >> 24);
}

__global__ void agg_i8(const uint2* __restrict__ S, const float* __restrict__ cs,
                       const float* __restrict__ dinv,
                       const int* __restrict__ rowp, const int* __restrict__ col,
                       uint4* __restrict__ OUT, int n) {
  int g = (blockIdx.x * blockDim.x + threadIdx.x) >> 4;
  int lane = threadIdx.x & 15;
  if (g >= n) return;
  float a[8];
  {
    uint2 q = S[(size_t)g * 16 + lane];
    float c = cs[g];
    int xx = (int)q.x, yy = (int)q.y;
    a[0] = c * (float)(signed char)(xx);
    a[1] = c * (float)(signed char)(xx >> 8);
    a[2] = c * (float)(signed char)(xx >> 16);
    a[3] = c * (float)(xx >> 24);
    a[4] = c * (float)(signed char)(yy);
    a[5] = c * (float)(signed char)(yy >> 8);
    a[6] = c * (float)(signed char)(yy >> 16);
    a[7] = c * (float)(yy >> 24);
  }
  int e0 = rowp[g], e1 = rowp[g + 1];
  int e = e0;
  for (; e + 3 < e1; e += 4) {
    int s0 = col[e], s1 = col[e + 1], s2 = col[e + 2], s3 = col[e + 3];
    uint2 q0 = S[(size_t)s0 * 16 + lane];
    uint2 q1 = S[(size_t)s1 * 16 + lane];
    uint2 q2 = S[(size_t)s2 * 16 + lane];
    uint2 q3 = S[(size_t)s3 * 16 + lane];
    float c0 = cs[s0], c1 = cs[s1], c2 = cs[s2], c3 = cs[s3];
    acc8(q0, c0, a); acc8(q1, c1, a); acc8(q2, c2, a); acc8(q3, c3, a);
  }
  for (; e < e1; e++) {
    int s = col[e];
    uint2 q = S[(size_t)s * 16 + lane];
    acc8(q, cs[s], a);
  }
  float d = dinv[g];
  uint4 o;
  o.x = pk2(a[0] * d, a[1] * d); o.y = pk2(a[2] * d, a[3] * d);
  o.z = pk2(a[4] * d, a[5] * d); o.w = pk2(a[6] * d, a[7] * d);
  OUT[(size_t)g * 16 + lane] = o;
}

// ------- MFMA GEMM (LDS-staged weights) -> int8 quantized state (layers 0,1) -------
// smem: phase 1/2 = W tile (128 rows x 17 uint4, padded -> 2-way bank = free);
// after MFMAs, reused as epilogue repack buffer (stride 144 B).

__global__ __launch_bounds__(256) void gemm_mfma_q8(
    const uint4* __restrict__ A, const uint4* __restrict__ WThi, const uint4* __restrict__ WTlo,
    const float* __restrict__ bias, const float* __restrict__ dinv,
    unsigned char* __restrict__ Sout, float* __restrict__ csout, int n) {
  __shared__ char smem[34816];          // max(128*17*16, 64*144)
  __shared__ float Lc[64];
  uint4* Wl = (uint4*)smem;
  int t = threadIdx.x;
  int lane = t & 63, wv = t >> 6;
  int m = lane & 15, quad = lane >> 4;
  int block0 = blockIdx.x * 64;
  int arow = block0 + wv * 16 + m;
  uint4 av[4];
  #pragma unroll
  for (int kb = 0; kb < 4; kb++)
    av[kb] = (arow < n) ? A[(size_t)arow * 16 + kb * 4 + quad] : make_uint4(0, 0, 0, 0);
  f32x4 acc[8];
  #pragma unroll
  for (int i = 0; i < 8; i++) acc[i] = (f32x4){0.f, 0.f, 0.f, 0.f};

  // phase hi
  #pragma unroll
  for (int i = 0; i < 8; i++) {
    int idx = t + i * 256;
    Wl[(idx >> 4) * 17 + (idx & 15)] = WThi[idx];
  }
  __syncthreads();
  #pragma unroll
  for (int kb = 0; kb < 4; kb++) {
    short8 af = __builtin_bit_cast(short8, av[kb]);
    #pragma unroll
    for (int nt = 0; nt < 8; nt++) {
      uint4 bh = Wl[(nt * 16 + m) * 17 + kb * 4 + quad];
      acc[nt] = __builtin_amdgcn_mfma_f32_16x16x32_bf16(af, __builtin_bit_cast(short8, bh), acc[nt], 0, 0, 0);
    }
  }
  __syncthreads();
  // phase lo
  #pragma unroll
  for (int i = 0; i < 8; i++) {
    int idx = t + i * 256;
    Wl[(idx >> 4) * 17 + (idx & 15)] = WTlo[idx];
  }
  __syncthreads();
  #pragma unroll
  for (int kb = 0; kb < 4; kb++) {
    short8 af = __builtin_bit_cast(short8, av[kb]);
    #pragma unroll
    for (int nt = 0; nt < 8; nt++) {
      uint4 bl = Wl[(nt * 16 + m) * 17 + kb * 4 + quad];
      acc[nt] = __builtin_amdgcn_mfma_f32_16x16x32_bf16(af, __builtin_bit_cast(short8, bl), acc[nt], 0, 0, 0);
    }
  }
  __syncthreads();   // W tile dead; smem becomes repack buffer

  #pragma unroll
  for (int r = 0; r < 4; r++) {
    int lrow = wv * 16 + quad * 4 + r;
    int grow = block0 + lrow;
    float sc = (grow < n) ? dinv[grow] : 0.f;
    float v[8];
    float mx = 0.f;
    #pragma unroll
    for (int nt = 0; nt < 8; nt++) {
      v[nt] = fmaxf(acc[nt][r] + bias[nt * 16 + m], 0.f) * sc;
      mx = fmaxf(mx, v[nt]);
    }
    mx = fmaxf(mx, __shfl_xor(mx, 1));
    mx = fmaxf(mx, __shfl_xor(mx, 2));
    mx = fmaxf(mx, __shfl_xor(mx, 4));
    mx = fmaxf(mx, __shfl_xor(mx, 8));
    float c = mx * (1.0f / 127.0f);
    float rinv = (mx > 0.f) ? 127.0f / mx : 0.f;
    #pragma unroll
    for (int nt = 0; nt < 8; nt++) {
      smem[lrow * 144 + nt * 16 + m] = (char)(int)rintf(v[nt] * rinv);
    }
    if (m == 0) Lc[lrow] = c;
  }
  __syncthreads();
  for (int i = t; i < 512; i += 256) {
    int lrow = i >> 3, seg = i & 7;
    int grow = block0 + lrow;
    if (grow < n)
      ((uint4*)Sout)[(size_t)grow * 8 + seg] = *(const uint4*)&smem[lrow * 144 + seg * 16];
  }
  if (t < 64 && block0 + t < n) csout[block0 + t] = Lc[t];
}

// ------- MFMA GEMM (LDS-staged weights) -> bf16 out (final layer) -------

__global__ __launch_bounds__(256) void gemm_mfma(
    const uint4* __restrict__ A, const uint4* __restrict__ WThi, const uint4* __restrict__ WTlo,
    const float* __restrict__ bias, unsigned short* __restrict__ Y, int n) {
  __shared__ char smem[34816];          // W tile, then bf16 repack (stride 272 B)
  uint4* Wl = (uint4*)smem;
  int t = threadIdx.x;
  int lane = t & 63, wv = t >> 6;
  int m = lane & 15, quad = lane >> 4;
  int block0 = blockIdx.x * 64;
  int arow = block0 + wv * 16 + m;
  uint4 av[4];
  #pragma unroll
  for (int kb = 0; kb < 4; kb++)
    av[kb] = (arow < n) ? A[(size_t)arow * 16 + kb * 4 + quad] : make_uint4(0, 0, 0, 0);
  f32x4 acc[8];
  #pragma unroll
  for (int i = 0; i < 8; i++) acc[i] = (f32x4){0.f, 0.f, 0.f, 0.f};

  #pragma unroll
  for (int i = 0; i < 8; i++) {
    int idx = t + i * 256;
    Wl[(idx >> 4) * 17 + (idx & 15)] = WThi[idx];
  }
  __syncthreads();
  #pragma unroll
  for (int kb = 0; kb < 4; kb++) {
    short8 af = __builtin_bit_cast(short8, av[kb]);
    #pragma unroll
    for (int nt = 0; nt < 8; nt++) {
      uint4 bh = Wl[(nt * 16 + m) * 17 + kb * 4 + quad];
      acc[nt] = __builtin_amdgcn_mfma_f32_16x16x32_bf16(af, __builtin_bit_cast(short8, bh), acc[nt], 0, 0, 0);
    }
  }
  __syncthreads();
  #pragma unroll
  for (int i = 0; i < 8; i++) {
    int idx = t + i * 256;
    Wl[(idx >> 4) * 17 + (idx & 15)] = WTlo[idx];
  }
  __syncthreads();
  #pragma unroll
  for (int kb = 0; kb < 4; kb++) {
    short8 af = __builtin_bit_cast(short8, av[kb]);
    #pragma unroll
    for (int nt = 0; nt < 8; nt++) {
      uint4 bl = Wl[(nt * 16 + m) * 17 + kb * 4 + quad];
      acc[nt] = __builtin_amdgcn_mfma_f32_16x16x32_bf16(af, __builtin_bit_cast(short8, bl), acc[nt], 0, 0, 0);
    }
  }
  __syncthreads();

  unsigned short* Ls = (unsigned short*)smem;
  #pragma unroll
  for (int r = 0; r < 4; r++) {
    int lrow = wv * 16 + quad * 4 + r;
    #pragma unroll
    for (int nt = 0; nt < 8; nt++) {
      float v = fmaxf(acc[nt][r] + bias[nt * 16 + m], 0.f);
      Ls[lrow * 136 + nt * 16 + m] = f2bf(v);
    }
  }
  __syncthreads();
  for (int i = t; i < 1024; i += 256) {
    int lrow = i >> 4, seg = i & 15;
    int grow = block0 + lrow;
    if (grow < n)
      ((uint4*)Y)[(size_t)grow * 16 + seg] = *(const uint4*)&smem[lrow * 272 + seg * 16];
  }
}

// ------- mean pool (batch sorted, bf16 input; parallel) -------

__global__ void pool_kernel(const unsigned short* __restrict__ X, const int* __restrict__ batch,
                            float* __restrict__ pooled, float* __restrict__ gcnt, int n) {
  int t = threadIdx.x;
  int r0 = blockIdx.x * 64;
  if (r0 >= n) return;
  int r1 = min(r0 + 64, n);
  int g = batch[r0];
  float acc = 0.f, cl = 0.f;
  for (int r = r0; r < r1; r++) {
    int gr = batch[r];
    if (gr != g) {
      atomicAdd(&pooled[g * HDIM + t], acc);
      if (t == 0) atomicAdd(&gcnt[g], cl);
      acc = 0.f; cl = 0.f; g = gr;
    }
    acc += __uint_as_float((unsigned)X[(size_t)r * HDIM + t] << 16);
    cl += 1.f;
  }
  atomicAdd(&pooled[g * HDIM + t], acc);
  if (t == 0) atomicAdd(&gcnt[g], cl);
}

// ------- classifier head -------

__global__ void cls_kernel(const float* __restrict__ pooled, const float* __restrict__ gcnt,
                           const float* __restrict__ Wc1, const float* __restrict__ bc1,
                           const float* __restrict__ Wc2, const float* __restrict__ bc2,
                           float* __restrict__ out) {
  __shared__ float p[HDIM];
  __shared__ float r0s[HDIM], r1s[HDIM];
  int g = blockIdx.x, t = threadIdx.x;
  float c = fmaxf(gcnt[g], 1.0f);
  p[t] = pooled[g * HDIM + t] / c;
  __syncthreads();
  float acc = bc1[t];
  for (int k = 0; k < HDIM; k++) {
    acc += p[k] * (Wc1[k * HDIM + t] + Wc1[(HDIM + k) * HDIM + t]);
  }
  float h = fmaxf(acc, 0.f);
  r0s[t] = h * Wc2[t * 2 + 0];
  r1s[t] = h * Wc2[t * 2 + 1];
  __syncthreads();
  for (int s2 = 64; s2 > 0; s2 >>= 1) {
    if (t < s2) { r0s[t] += r0s[t + s2]; r1s[t] += r1s[t + s2]; }
    __syncthreads();
  }
  if (t == 0) {
    out[g * 2 + 0] = r0s[0] + bc2[0];
    out[g * 2 + 1] = r1s[0] + bc2[1];
  }
}

// ------- launch -------

extern "C" void kernel_launch(void* const* d_in, const int* in_sizes, int n_in,
                              void* d_out, int out_size, void* d_ws, size_t ws_size,
                              hipStream_t stream) {
  const float* x   = (const float*)d_in[0];
  const int*   ei  = (const int*)d_in[1];
  const int*   bat = (const int*)d_in[2];
  const float* W0  = (const float*)d_in[3];
  const float* b0  = (const float*)d_in[4];
  const float* W1  = (const float*)d_in[5];
  const float* b1  = (const float*)d_in[6];
  const float* W2  = (const float*)d_in[7];
  const float* b2  = (const float*)d_in[8];
  const float* Wc1 = (const float*)d_in[9];
  const float* bc1 = (const float*)d_in[10];
  const float* Wc2 = (const float*)d_in[11];
  const float* bc2 = (const float*)d_in[12];
  float* out = (float*)d_out;

  int N = in_sizes[0] / HDIM;
  int E = in_sizes[1] / 2;
  const int* src = ei;
  const int* dst = ei + E;

  int NB1 = (N + 255) >> 8;
  int G = (E + CHUNK - 1) / CHUNK;
  int M = NB1 * G;

  char* ws = (char*)d_ws;
  size_t off = 0;
  auto alloc = [&](size_t bytes) -> void* {
    void* p = (void*)(ws + off);
    off += (bytes + 511) & ~(size_t)511;
    return p;
  };
  unsigned char* Sa = (unsigned char*)alloc((size_t)N * HDIM * 2);
  unsigned char* Sb = Sa + (size_t)N * HDIM;
  unsigned short* H = (unsigned short*)Sa;
  unsigned short* Abuf = (unsigned short*)alloc((size_t)N * HDIM * 2);
  float* csa  = (float*)alloc((size_t)N * 4);
  float* csb  = (float*)alloc((size_t)N * 4);
  float* cs_base = (float*)alloc((size_t)N * 4);
  float* dinv = (float*)alloc((size_t)N * 4);
  int*   rowp = (int*)alloc((size_t)(NB1 * 256 + 2) * 4);
  int*   colv = (int*)alloc((size_t)E * 4);
  uint2* sp   = (uint2*)alloc((size_t)E * 8);
  float* pooled = (float*)alloc((size_t)GCOUNT * HDIM * 4);
  float* gcnt   = (float*)alloc((size_t)GCOUNT * 4);
  unsigned short* wt_hi[3], *wt_lo[3];
  for (int i = 0; i < 3; i++) {
    wt_hi[i] = (unsigned short*)alloc(HDIM * HDIM * 2);
    wt_lo[i] = (unsigned short*)alloc(HDIM * HDIM * 2);
  }
  int* gcount = (int*)alloc((size_t)(M + 2) * 4);
  int nbM = (M + 255) / 256;
  int* bsum = (int*)alloc((size_t)nbM * 4);

  // 1. mega1
  int pz = (GCOUNT * HDIM + GCOUNT + 255) / 256;
  int psb = (N + 15) / 16;
  mega1<<<192 + pz + G + psb, 256, 0, stream>>>(W0, W1, W2,
      wt_hi[0], wt_lo[0], wt_hi[1], wt_lo[1], wt_hi[2], wt_lo[2],
      pooled, gcnt, pz, dst, E, G, NB1, gcount,
      x, (uint2*)Sa, cs_base, N);

  // 2-3. scans
  scanA<<<nbM, 256, 0, stream>>>(gcount, bsum, M);
  scanB<<<(M + 1023) / 1024, 512, 0, stream>>>(gcount, bsum, nbM, M);

  // 4-5. scatter + fine CSR
  rs_scatter<<<G, 256, 0, stream>>>(src, dst, gcount, E, G, NB1, sp);
  csr_fine<<<NB1, 256, 0, stream>>>(sp, gcount, E, G, NB1, rowp, colv,
      dinv, cs_base, csa, N);

  // 6-11. agg + gemm ping-pong
  int aggBlocks = (N + 15) / 16;
  int gemmBlocks = (N + 63) / 64;

  agg_i8<<<aggBlocks, 256, 0, stream>>>((const uint2*)Sa, csa, dinv, rowp, colv, (uint4*)Abuf, N);
  gemm_mfma_q8<<<gemmBlocks, 256, 0, stream>>>((const uint4*)Abuf, (const uint4*)wt_hi[0],
      (const uint4*)wt_lo[0], b0, dinv, Sb, csb, N);

  agg_i8<<<aggBlocks, 256, 0, stream>>>((const uint2*)Sb, csb, dinv, rowp, colv, (uint4*)Abuf, N);
  gemm_mfma_q8<<<gemmBlocks, 256, 0, stream>>>((const uint4*)Abuf, (const uint4*)wt_hi[1],
      (const uint4*)wt_lo[1], b1, dinv, Sa, csa, N);

  agg_i8<<<aggBlocks, 256, 0, stream>>>((const uint2*)Sa, csa, dinv, rowp, colv, (uint4*)Abuf, N);
  gemm_mfma<<<gemmBlocks, 256, 0, stream>>>((const uint4*)Abuf, (const uint4*)wt_hi[2],
      (const uint4*)wt_lo[2], b2, H, N);

  // 12-13. pool + classifier
  pool_kernel<<<(N + 63) / 64, 128, 0, stream>>>(H, bat, pooled, gcnt, N);
  cls_kernel<<<GCOUNT, HDIM, 0, stream>>>(pooled, gcnt, Wc1, bc1, Wc2, bc2, out);
}

// Round 12
// 362.578 us; speedup vs baseline: 1.7449x; 1.0568x over previous
//
#include <hip/hip_runtime.h>

#define HDIM 128
#define GCOUNT 64
#define CHUNK 2048

// ---- bf16 helpers (manual, RNE) ----
__device__ __forceinline__ float bfl(unsigned u) { return __uint_as_float(u << 16); }
__device__ __forceinline__ float bfh(unsigned u) { return __uint_as_float(u & 0xffff0000u); }
__device__ __forceinline__ unsigned short f2bf(float f) {
  unsigned u = __float_as_uint(f);
  unsigned r = (u + 0x7fffu + ((u >> 16) & 1u)) >> 16;
  return (unsigned short)r;
}
__device__ __forceinline__ unsigned pk2(float a, float b) {
  return (unsigned)f2bf(a) | ((unsigned)f2bf(b) << 16);
}

typedef __attribute__((ext_vector_type(8))) short short8;
typedef __attribute__((ext_vector_type(4))) float f32x4;

__device__ __forceinline__ unsigned qb(float v, float rinv) {
  int q = (int)rintf(v * rinv);
  return (unsigned)(q & 0xff);
}

// ------- mega1: weight transpose | zero pooled/gcnt | coarse hist | prescale int8 -------

__global__ void mega1(const float* __restrict__ W0, const float* __restrict__ W1,
                      const float* __restrict__ W2,
                      unsigned short* __restrict__ h0, unsigned short* __restrict__ l0,
                      unsigned short* __restrict__ h1, unsigned short* __restrict__ l1,
                      unsigned short* __restrict__ h2, unsigned short* __restrict__ l2,
                      float* __restrict__ pooled, float* __restrict__ gcnt, int pz,
                      const int* __restrict__ dst, int E, int G, int NB1,
                      int* __restrict__ gcount,
                      const float* __restrict__ x, uint2* __restrict__ S,
                      float* __restrict__ cs_base, int n) {
  __shared__ int hist[512];
  int b = blockIdx.x, t = threadIdx.x;
  if (b < 192) {
    int w = b >> 6;
    int idx = (b & 63) * 256 + t;
    const float* W = (w == 0) ? W0 : (w == 1) ? W1 : W2;
    unsigned short* hi = (w == 0) ? h0 : (w == 1) ? h1 : h2;
    unsigned short* lo = (w == 0) ? l0 : (w == 1) ? l1 : l2;
    int k = idx >> 7, nn = idx & 127;
    float wv = W[idx];
    unsigned short h = f2bf(wv);
    float hf = __uint_as_float((unsigned)h << 16);
    unsigned short l = f2bf(wv - hf);
    hi[nn * 128 + k] = h;
    lo[nn * 128 + k] = l;
  } else if (b < 192 + pz) {
    int i = (b - 192) * 256 + t;
    if (i < GCOUNT * HDIM) pooled[i] = 0.f;
    else if (i - GCOUNT * HDIM < GCOUNT) gcnt[i - GCOUNT * HDIM] = 0.f;
  } else if (b < 192 + pz + G) {
    int blk = b - 192 - pz;
    for (int i = t; i < NB1; i += 256) hist[i] = 0;
    __syncthreads();
    int base = blk * CHUNK;
    #pragma unroll
    for (int j = 0; j < CHUNK / 256; j++) {
      int e = base + j * 256 + t;
      if (e < E) atomicAdd(&hist[dst[e] >> 8], 1);
    }
    __syncthreads();
    for (int i = t; i < NB1; i += 256) gcount[i * G + blk] = hist[i];
  } else {
    int idx = (b - 192 - pz - G) * 16 + (t >> 4);
    int l = t & 15;
    int ridx = min(idx, n - 1);
    float4 f0 = ((const float4*)x)[(size_t)ridx * 32 + l * 2];
    float4 f1 = ((const float4*)x)[(size_t)ridx * 32 + l * 2 + 1];
    float v0 = f0.x, v1 = f0.y, v2 = f0.z, v3 = f0.w;
    float v4 = f1.x, v5 = f1.y, v6 = f1.z, v7 = f1.w;
    float mx = fmaxf(fmaxf(fmaxf(fabsf(v0), fabsf(v1)), fmaxf(fabsf(v2), fabsf(v3))),
                     fmaxf(fmaxf(fabsf(v4), fabsf(v5)), fmaxf(fabsf(v6), fabsf(v7))));
    mx = fmaxf(mx, __shfl_xor(mx, 1));
    mx = fmaxf(mx, __shfl_xor(mx, 2));
    mx = fmaxf(mx, __shfl_xor(mx, 4));
    mx = fmaxf(mx, __shfl_xor(mx, 8));
    float c = mx * (1.0f / 127.0f);
    float rinv = (mx > 0.f) ? 127.0f / mx : 0.f;
    if (idx < n) {
      unsigned lo = qb(v0, rinv) | (qb(v1, rinv) << 8) | (qb(v2, rinv) << 16) | (qb(v3, rinv) << 24);
      unsigned hi = qb(v4, rinv) | (qb(v5, rinv) << 8) | (qb(v6, rinv) << 16) | (qb(v7, rinv) << 24);
      S[(size_t)idx * 16 + l] = make_uint2(lo, hi);
      if (l == 0) cs_base[idx] = c;
    }
  }
}

// ------- scanA (1024 threads) / scanB -------

__global__ void scanA(int* __restrict__ g, int* __restrict__ bsum, int M) {
  __shared__ int sh[1024];
  int t = threadIdx.x;
  int i = blockIdx.x * 1024 + t;
  int v = (i < M) ? g[i] : 0;
  sh[t] = v;
  __syncthreads();
  for (int off = 1; off < 1024; off <<= 1) {
    int u = (t >= off) ? sh[t - off] : 0;
    __syncthreads();
    sh[t] += u;
    __syncthreads();
  }
  if (i < M) g[i] = sh[t] - v;
  if (t == 1023) bsum[blockIdx.x] = sh[1023];
}

__global__ void scanB(int* __restrict__ g, const int* __restrict__ bsum, int nb, int M) {
  __shared__ int sh[512];
  int t = threadIdx.x;  // 1024 threads; low 512 do the bsum scan
  if (t < 512) sh[t] = (t < nb) ? bsum[t] : 0;
  __syncthreads();
  for (int off = 1; off < 512; off <<= 1) {
    int u = (t < 512 && t >= off) ? sh[t - off] : 0;
    __syncthreads();
    if (t < 512) sh[t] += u;
    __syncthreads();
  }
  #pragma unroll
  for (int k = 0; k < 2; k++) {
    int i = blockIdx.x * 2048 + k * 1024 + t;
    if (i < M) {
      int j = i >> 10;
      if (j) g[i] += sh[j - 1];
    }
  }
}

// ------- rs_scatter: group (dst,src) by coarse bucket (dst>>8), LDS atomics only -------

__global__ void rs_scatter(const int* __restrict__ src, const int* __restrict__ dst,
                           const int* __restrict__ gscan, int E, int G, int NB1,
                           uint2* __restrict__ sp) {
  __shared__ int run[512];
  int blk = blockIdx.x, t = threadIdx.x;
  for (int i = t; i < NB1; i += 256) run[i] = gscan[i * G + blk];
  __syncthreads();
  int base = blk * CHUNK;
  #pragma unroll
  for (int j = 0; j < CHUNK / 256; j++) {
    int e = base + j * 256 + t;
    if (e < E) {
      int d = dst[e];
      int pos = atomicAdd(&run[d >> 8], 1);
      sp[pos] = make_uint2((unsigned)d, (unsigned)src[e]);
    }
  }
}

// ------- csr_fine (512 threads): rowp/col/dinv/cs per coarse bucket -------

__global__ void csr_fine(const uint2* __restrict__ sp, const int* __restrict__ gscan,
                         int E, int G, int NB1,
                         int* __restrict__ rowp, int* __restrict__ colv,
                         float* __restrict__ dinv, const float* __restrict__ cs_base,
                         float* __restrict__ cs, int n) {
  __shared__ int hist[256];
  __shared__ int scn[256];
  __shared__ int run2[256];
  int hb = blockIdx.x, t = threadIdx.x;
  int O = gscan[hb * G];
  int Oe = (hb == NB1 - 1) ? E : gscan[(hb + 1) * G];
  if (t < 256) hist[t] = 0;
  __syncthreads();
  for (int e = O + t; e < Oe; e += 512) atomicAdd(&hist[sp[e].x & 255], 1);
  __syncthreads();
  int v = 0;
  if (t < 256) { v = hist[t]; scn[t] = v; }
  __syncthreads();
  for (int off = 1; off < 256; off <<= 1) {
    int u = (t < 256 && t >= off) ? scn[t - off] : 0;
    __syncthreads();
    if (t < 256) scn[t] += u;
    __syncthreads();
  }
  if (t < 256) {
    int excl = scn[t] - v;
    run2[t] = O + excl;
    int d = (hb << 8) + t;
    rowp[d] = O + excl;
    if (d < n) {
      float dv = rsqrtf((float)v + 1.0f);
      dinv[d] = dv;
      cs[d] = cs_base[d] * dv;
    }
  }
  if (hb == NB1 - 1 && t == 0) rowp[n] = E;
  __syncthreads();
  for (int e = O + t; e < Oe; e += 512) {
    uint2 p = sp[e];
    int pos = atomicAdd(&run2[p.x & 255], 1);
    colv[pos] = (int)p.y;
  }
}

// ------- aggregation (int8 state, per-row scale; 16-lane groups; 8-deep unroll) -------

__device__ __forceinline__ void acc8(uint2 v, float c, float* a) {
  int xx = (int)v.x, yy = (int)v.y;
  a[0] += c * (float)(signed char)(xx);
  a[1] += c * (float)(signed char)(xx >> 8);
  a[2] += c * (float)(signed char)(xx >> 16);
  a[3] += c * (float)(xx >> 24);
  a[4] += c * (float)(signed char)(yy);
  a[5] += c * (float)(signed char)(yy >> 8);
  a[6] += c * (float)(signed char)(yy >> 16);
  a[7] += c * (float)(yy >> 24);
}

__global__ void agg_i8(const uint2* __restrict__ S, const float* __restrict__ cs,
                       const float* __restrict__ dinv,
                       const int* __restrict__ rowp, const int* __restrict__ col,
                       uint4* __restrict__ OUT, int n) {
  int g = (blockIdx.x * blockDim.x + threadIdx.x) >> 4;
  int lane = threadIdx.x & 15;
  if (g >= n) return;
  float a[8];
  {
    uint2 q = S[(size_t)g * 16 + lane];
    float c = cs[g];
    int xx = (int)q.x, yy = (int)q.y;
    a[0] = c * (float)(signed char)(xx);
    a[1] = c * (float)(signed char)(xx >> 8);
    a[2] = c * (float)(signed char)(xx >> 16);
    a[3] = c * (float)(xx >> 24);
    a[4] = c * (float)(signed char)(yy);
    a[5] = c * (float)(signed char)(yy >> 8);
    a[6] = c * (float)(signed char)(yy >> 16);
    a[7] = c * (float)(yy >> 24);
  }
  int e0 = rowp[g], e1 = rowp[g + 1];
  int e = e0;
  for (; e + 7 < e1; e += 8) {
    int s0 = col[e],     s1 = col[e + 1], s2 = col[e + 2], s3 = col[e + 3];
    int s4 = col[e + 4], s5 = col[e + 5], s6 = col[e + 6], s7 = col[e + 7];
    uint2 q0 = S[(size_t)s0 * 16 + lane];
    uint2 q1 = S[(size_t)s1 * 16 + lane];
    uint2 q2 = S[(size_t)s2 * 16 + lane];
    uint2 q3 = S[(size_t)s3 * 16 + lane];
    uint2 q4 = S[(size_t)s4 * 16 + lane];
    uint2 q5 = S[(size_t)s5 * 16 + lane];
    uint2 q6 = S[(size_t)s6 * 16 + lane];
    uint2 q7 = S[(size_t)s7 * 16 + lane];
    float c0 = cs[s0], c1 = cs[s1], c2 = cs[s2], c3 = cs[s3];
    float c4 = cs[s4], c5 = cs[s5], c6 = cs[s6], c7 = cs[s7];
    acc8(q0, c0, a); acc8(q1, c1, a); acc8(q2, c2, a); acc8(q3, c3, a);
    acc8(q4, c4, a); acc8(q5, c5, a); acc8(q6, c6, a); acc8(q7, c7, a);
  }
  for (; e + 3 < e1; e += 4) {
    int s0 = col[e], s1 = col[e + 1], s2 = col[e + 2], s3 = col[e + 3];
    uint2 q0 = S[(size_t)s0 * 16 + lane];
    uint2 q1 = S[(size_t)s1 * 16 + lane];
    uint2 q2 = S[(size_t)s2 * 16 + lane];
    uint2 q3 = S[(size_t)s3 * 16 + lane];
    float c0 = cs[s0], c1 = cs[s1], c2 = cs[s2], c3 = cs[s3];
    acc8(q0, c0, a); acc8(q1, c1, a); acc8(q2, c2, a); acc8(q3, c3, a);
  }
  for (; e < e1; e++) {
    int s = col[e];
    uint2 q = S[(size_t)s * 16 + lane];
    acc8(q, cs[s], a);
  }
  float d = dinv[g];
  uint4 o;
  o.x = pk2(a[0] * d, a[1] * d); o.y = pk2(a[2] * d, a[3] * d);
  o.z = pk2(a[4] * d, a[5] * d); o.w = pk2(a[6] * d, a[7] * d);
  OUT[(size_t)g * 16 + lane] = o;
}

// ------- MFMA GEMM (LDS-staged weights) -> int8 quantized state (layers 0,1) -------

__global__ __launch_bounds__(256) void gemm_mfma_q8(
    const uint4* __restrict__ A, const uint4* __restrict__ WThi, const uint4* __restrict__ WTlo,
    const float* __restrict__ bias, const float* __restrict__ dinv,
    unsigned char* __restrict__ Sout, float* __restrict__ csout, int n) {
  __shared__ char smem[34816];
  __shared__ float Lc[64];
  uint4* Wl = (uint4*)smem;
  int t = threadIdx.x;
  int lane = t & 63, wv = t >> 6;
  int m = lane & 15, quad = lane >> 4;
  int block0 = blockIdx.x * 64;
  int arow = block0 + wv * 16 + m;
  uint4 av[4];
  #pragma unroll
  for (int kb = 0; kb < 4; kb++)
    av[kb] = (arow < n) ? A[(size_t)arow * 16 + kb * 4 + quad] : make_uint4(0, 0, 0, 0);
  f32x4 acc[8];
  #pragma unroll
  for (int i = 0; i < 8; i++) acc[i] = (f32x4){0.f, 0.f, 0.f, 0.f};

  #pragma unroll
  for (int i = 0; i < 8; i++) {
    int idx = t + i * 256;
    Wl[(idx >> 4) * 17 + (idx & 15)] = WThi[idx];
  }
  __syncthreads();
  #pragma unroll
  for (int kb = 0; kb < 4; kb++) {
    short8 af = __builtin_bit_cast(short8, av[kb]);
    #pragma unroll
    for (int nt = 0; nt < 8; nt++) {
      uint4 bh = Wl[(nt * 16 + m) * 17 + kb * 4 + quad];
      acc[nt] = __builtin_amdgcn_mfma_f32_16x16x32_bf16(af, __builtin_bit_cast(short8, bh), acc[nt], 0, 0, 0);
    }
  }
  __syncthreads();
  #pragma unroll
  for (int i = 0; i < 8; i++) {
    int idx = t + i * 256;
    Wl[(idx >> 4) * 17 + (idx & 15)] = WTlo[idx];
  }
  __syncthreads();
  #pragma unroll
  for (int kb = 0; kb < 4; kb++) {
    short8 af = __builtin_bit_cast(short8, av[kb]);
    #pragma unroll
    for (int nt = 0; nt < 8; nt++) {
      uint4 bl = Wl[(nt * 16 + m) * 17 + kb * 4 + quad];
      acc[nt] = __builtin_amdgcn_mfma_f32_16x16x32_bf16(af, __builtin_bit_cast(short8, bl), acc[nt], 0, 0, 0);
    }
  }
  __syncthreads();

  #pragma unroll
  for (int r = 0; r < 4; r++) {
    int lrow = wv * 16 + quad * 4 + r;
    int grow = block0 + lrow;
    float sc = (grow < n) ? dinv[grow] : 0.f;
    float v[8];
    float mx = 0.f;
    #pragma unroll
    for (int nt = 0; nt < 8; nt++) {
      v[nt] = fmaxf(acc[nt][r] + bias[nt * 16 + m], 0.f) * sc;
      mx = fmaxf(mx, v[nt]);
    }
    mx = fmaxf(mx, __shfl_xor(mx, 1));
    mx = fmaxf(mx, __shfl_xor(mx, 2));
    mx = fmaxf(mx, __shfl_xor(mx, 4));
    mx = fmaxf(mx, __shfl_xor(mx, 8));
    float c = mx * (1.0f / 127.0f);
    float rinv = (mx > 0.f) ? 127.0f / mx : 0.f;
    #pragma unroll
    for (int nt = 0; nt < 8; nt++) {
      smem[lrow * 144 + nt * 16 + m] = (char)(int)rintf(v[nt] * rinv);
    }
    if (m == 0) Lc[lrow] = c;
  }
  __syncthreads();
  for (int i = t; i < 512; i += 256) {
    int lrow = i >> 3, seg = i & 7;
    int grow = block0 + lrow;
    if (grow < n)
      ((uint4*)Sout)[(size_t)grow * 8 + seg] = *(const uint4*)&smem[lrow * 144 + seg * 16];
  }
  if (t < 64 && block0 + t < n) csout[block0 + t] = Lc[t];
}

// ------- MFMA GEMM (LDS-staged weights) -> bf16 out (final layer) -------

__global__ __launch_bounds__(256) void gemm_mfma(
    const uint4* __restrict__ A, const uint4* __restrict__ WThi, const uint4* __restrict__ WTlo,
    const float* __restrict__ bias, unsigned short* __restrict__ Y, int n) {
  __shared__ char smem[34816];
  uint4* Wl = (uint4*)smem;
  int t = threadIdx.x;
  int lane = t & 63, wv = t >> 6;
  int m = lane & 15, quad = lane >> 4;
  int block0 = blockIdx.x * 64;
  int arow = block0 + wv * 16 + m;
  uint4 av[4];
  #pragma unroll
  for (int kb = 0; kb < 4; kb++)
    av[kb] = (arow < n) ? A[(size_t)arow * 16 + kb * 4 + quad] : make_uint4(0, 0, 0, 0);
  f32x4 acc[8];
  #pragma unroll
  for (int i = 0; i < 8; i++) acc[i] = (f32x4){0.f, 0.f, 0.f, 0.f};

  #pragma unroll
  for (int i = 0; i < 8; i++) {
    int idx = t + i * 256;
    Wl[(idx >> 4) * 17 + (idx & 15)] = WThi[idx];
  }
  __syncthreads();
  #pragma unroll
  for (int kb = 0; kb < 4; kb++) {
    short8 af = __builtin_bit_cast(short8, av[kb]);
    #pragma unroll
    for (int nt = 0; nt < 8; nt++) {
      uint4 bh = Wl[(nt * 16 + m) * 17 + kb * 4 + quad];
      acc[nt] = __builtin_amdgcn_mfma_f32_16x16x32_bf16(af, __builtin_bit_cast(short8, bh), acc[nt], 0, 0, 0);
    }
  }
  __syncthreads();
  #pragma unroll
  for (int i = 0; i < 8; i++) {
    int idx = t + i * 256;
    Wl[(idx >> 4) * 17 + (idx & 15)] = WTlo[idx];
  }
  __syncthreads();
  #pragma unroll
  for (int kb = 0; kb < 4; kb++) {
    short8 af = __builtin_bit_cast(short8, av[kb]);
    #pragma unroll
    for (int nt = 0; nt < 8; nt++) {
      uint4 bl = Wl[(nt * 16 + m) * 17 + kb * 4 + quad];
      acc[nt] = __builtin_amdgcn_mfma_f32_16x16x32_bf16(af, __builtin_bit_cast(short8, bl), acc[nt], 0, 0, 0);
    }
  }
  __syncthreads();

  unsigned short* Ls = (unsigned short*)smem;
  #pragma unroll
  for (int r = 0; r < 4; r++) {
    int lrow = wv * 16 + quad * 4 + r;
    #pragma unroll
    for (int nt = 0; nt < 8; nt++) {
      float v = fmaxf(acc[nt][r] + bias[nt * 16 + m], 0.f);
      Ls[lrow * 136 + nt * 16 + m] = f2bf(v);
    }
  }
  __syncthreads();
  for (int i = t; i < 1024; i += 256) {
    int lrow = i >> 4, seg = i & 15;
    int grow = block0 + lrow;
    if (grow < n)
      ((uint4*)Y)[(size_t)grow * 16 + seg] = *(const uint4*)&smem[lrow * 272 + seg * 16];
  }
}

// ------- mean pool (batch sorted, bf16 input; parallel) -------

__global__ void pool_kernel(const unsigned short* __restrict__ X, const int* __restrict__ batch,
                            float* __restrict__ pooled, float* __restrict__ gcnt, int n) {
  int t = threadIdx.x;
  int r0 = blockIdx.x * 64;
  if (r0 >= n) return;
  int r1 = min(r0 + 64, n);
  int g = batch[r0];
  float acc = 0.f, cl = 0.f;
  for (int r = r0; r < r1; r++) {
    int gr = batch[r];
    if (gr != g) {
      atomicAdd(&pooled[g * HDIM + t], acc);
      if (t == 0) atomicAdd(&gcnt[g], cl);
      acc = 0.f; cl = 0.f; g = gr;
    }
    acc += __uint_as_float((unsigned)X[(size_t)r * HDIM + t] << 16);
    cl += 1.f;
  }
  atomicAdd(&pooled[g * HDIM + t], acc);
  if (t == 0) atomicAdd(&gcnt[g], cl);
}

// ------- classifier head -------

__global__ void cls_kernel(const float* __restrict__ pooled, const float* __restrict__ gcnt,
                           const float* __restrict__ Wc1, const float* __restrict__ bc1,
                           const float* __restrict__ Wc2, const float* __restrict__ bc2,
                           float* __restrict__ out) {
  __shared__ float p[HDIM];
  __shared__ float r0s[HDIM], r1s[HDIM];
  int g = blockIdx.x, t = threadIdx.x;
  float c = fmaxf(gcnt[g], 1.0f);
  p[t] = pooled[g * HDIM + t] / c;
  __syncthreads();
  float acc = bc1[t];
  for (int k = 0; k < HDIM; k++) {
    acc += p[k] * (Wc1[k * HDIM + t] + Wc1[(HDIM + k) * HDIM + t]);
  }
  float h = fmaxf(acc, 0.f);
  r0s[t] = h * Wc2[t * 2 + 0];
  r1s[t] = h * Wc2[t * 2 + 1];
  __syncthreads();
  for (int s2 = 64; s2 > 0; s2 >>= 1) {
    if (t < s2) { r0s[t] += r0s[t + s2]; r1s[t] += r1s[t + s2]; }
    __syncthreads();
  }
  if (t == 0) {
    out[g * 2 + 0] = r0s[0] + bc2[0];
    out[g * 2 + 1] = r1s[0] + bc2[1];
  }
}

// ------- launch -------

extern "C" void kernel_launch(void* const* d_in, const int* in_sizes, int n_in,
                              void* d_out, int out_size, void* d_ws, size_t ws_size,
                              hipStream_t stream) {
  const float* x   = (const float*)d_in[0];
  const int*   ei  = (const int*)d_in[1];
  const int*   bat = (const int*)d_in[2];
  const float* W0  = (const float*)d_in[3];
  const float* b0  = (const float*)d_in[4];
  const float* W1  = (const float*)d_in[5];
  const float* b1  = (const float*)d_in[6];
  const float* W2  = (const float*)d_in[7];
  const float* b2  = (const float*)d_in[8];
  const float* Wc1 = (const float*)d_in[9];
  const float* bc1 = (const float*)d_in[10];
  const float* Wc2 = (const float*)d_in[11];
  const float* bc2 = (const float*)d_in[12];
  float* out = (float*)d_out;

  int N = in_sizes[0] / HDIM;
  int E = in_sizes[1] / 2;
  const int* src = ei;
  const int* dst = ei + E;

  int NB1 = (N + 255) >> 8;
  int G = (E + CHUNK - 1) / CHUNK;
  int M = NB1 * G;

  char* ws = (char*)d_ws;
  size_t off = 0;
  auto alloc = [&](size_t bytes) -> void* {
    void* p = (void*)(ws + off);
    off += (bytes + 511) & ~(size_t)511;
    return p;
  };
  unsigned char* Sa = (unsigned char*)alloc((size_t)N * HDIM * 2);
  unsigned char* Sb = Sa + (size_t)N * HDIM;
  unsigned short* H = (unsigned short*)Sa;
  unsigned short* Abuf = (unsigned short*)alloc((size_t)N * HDIM * 2);
  float* csa  = (float*)alloc((size_t)N * 4);
  float* csb  = (float*)alloc((size_t)N * 4);
  float* cs_base = (float*)alloc((size_t)N * 4);
  float* dinv = (float*)alloc((size_t)N * 4);
  int*   rowp = (int*)alloc((size_t)(NB1 * 256 + 2) * 4);
  int*   colv = (int*)alloc((size_t)E * 4);
  uint2* sp   = (uint2*)alloc((size_t)E * 8);
  float* pooled = (float*)alloc((size_t)GCOUNT * HDIM * 4);
  float* gcnt   = (float*)alloc((size_t)GCOUNT * 4);
  unsigned short* wt_hi[3], *wt_lo[3];
  for (int i = 0; i < 3; i++) {
    wt_hi[i] = (unsigned short*)alloc(HDIM * HDIM * 2);
    wt_lo[i] = (unsigned short*)alloc(HDIM * HDIM * 2);
  }
  int* gcount = (int*)alloc((size_t)(M + 2) * 4);
  int nbM = (M + 1023) / 1024;
  int* bsum = (int*)alloc((size_t)nbM * 4);

  // 1. mega1
  int pz = (GCOUNT * HDIM + GCOUNT + 255) / 256;
  int psb = (N + 15) / 16;
  mega1<<<192 + pz + G + psb, 256, 0, stream>>>(W0, W1, W2,
      wt_hi[0], wt_lo[0], wt_hi[1], wt_lo[1], wt_hi[2], wt_lo[2],
      pooled, gcnt, pz, dst, E, G, NB1, gcount,
      x, (uint2*)Sa, cs_base, N);

  // 2-3. scans (1024-thread blocks; nbM <= 512 holds: M ~ 306k -> nbM ~ 299)
  scanA<<<nbM, 1024, 0, stream>>>(gcount, bsum, M);
  scanB<<<(M + 2047) / 2048, 1024, 0, stream>>>(gcount, bsum, nbM, M);

  // 4-5. scatter + fine CSR
  rs_scatter<<<G, 256, 0, stream>>>(src, dst, gcount, E, G, NB1, sp);
  csr_fine<<<NB1, 512, 0, stream>>>(sp, gcount, E, G, NB1, rowp, colv,
      dinv, cs_base, csa, N);

  // 6-11. agg + gemm ping-pong
  int aggBlocks = (N + 15) / 16;
  int gemmBlocks = (N + 63) / 64;

  agg_i8<<<aggBlocks, 256, 0, stream>>>((const uint2*)Sa, csa, dinv, rowp, colv, (uint4*)Abuf, N);
  gemm_mfma_q8<<<gemmBlocks, 256, 0, stream>>>((const uint4*)Abuf, (const uint4*)wt_hi[0],
      (const uint4*)wt_lo[0], b0, dinv, Sb, csb, N);

  agg_i8<<<aggBlocks, 256, 0, stream>>>((const uint2*)Sb, csb, dinv, rowp, colv, (uint4*)Abuf, N);
  gemm_mfma_q8<<<gemmBlocks, 256, 0, stream>>>((const uint4*)Abuf, (const uint4*)wt_hi[1],
      (const uint4*)wt_lo[1], b1, dinv, Sa, csa, N);

  agg_i8<<<aggBlocks, 256, 0, stream>>>((const uint2*)Sa, csa, dinv, rowp, colv, (uint4*)Abuf, N);
  gemm_mfma<<<gemmBlocks, 256, 0, stream>>>((const uint4*)Abuf, (const uint4*)wt_hi[2],
      (const uint4*)wt_lo[2], b2, H, N);

  // 12-13. pool + classifier
  pool_kernel<<<(N + 63) / 64, 128, 0, stream>>>(H, bat, pooled, gcnt, N);
  cls_kernel<<<GCOUNT, HDIM, 0, stream>>>(pooled, gcnt, Wc1, bc1, Wc2, bc2, out);
}